// Round 6
// baseline (13256.441 us; speedup 1.0000x reference)
//
#include <hip/hip_runtime.h>
#include <math.h>

#define B 128
#define PP 196
#define ENC 2048
#define DEC 512
#define ATTD 512
#define EMB 300
#define VV 10000
#define CAPLEN 51
#define TT 50
#define KP3 3072           // padded K: 512(h)+300(emb)+2048(gawe)+212 pad
#define KUSE 2880          // used K extent (rest is zero pad)
#define NPPAD 10112        // pred N padded to 158*64
#define NBLK 128           // persistent grid

static const long long OFF_PRED = 0LL;
static const long long OFF_CAPS = 64000000LL;
static const long long OFF_DECL = 64006528LL;
static const long long OFF_ALPH = 64006656LL;
static const long long OFF_SORT = 65261056LL;

typedef unsigned short ushort_t;
typedef unsigned int uint_t;
typedef short bf8 __attribute__((ext_vector_type(8)));
typedef float f4 __attribute__((ext_vector_type(4)));

__device__ __forceinline__ float sigf(float x){ return 1.f/(1.f+expf(-x)); }
__device__ __forceinline__ float b2f(ushort_t u){
  union{uint_t i; float f;} v; v.i = ((uint_t)u)<<16; return v.f;
}
__device__ __forceinline__ ushort_t f2b(float f){
  union{float f; uint_t i;} v; v.f = f;
  uint_t r = v.i + 0x7fffu + ((v.i>>16)&1u);
  return (ushort_t)(r>>16);
}
__device__ __forceinline__ uint_t pack2(float lo, float hi){
  return (uint_t)f2b(lo) | ((uint_t)f2b(hi)<<16);
}
__device__ __forceinline__ float2 b2x2(uint_t u){
  union{uint_t i; float f;} a,b; a.i = u<<16; b.i = u & 0xffff0000u;
  return make_float2(a.f, b.f);
}

// ---- device-scope grid barrier: monotone counter, BOUNDED spin (fail-safe) ----
__device__ __forceinline__ void gbar(int* bar, int target){
  __syncthreads();
  if (threadIdx.x == 0){
    __hip_atomic_fetch_add(bar, 1, __ATOMIC_ACQ_REL, __HIP_MEMORY_SCOPE_AGENT);
    int guard = 0;
    while (__hip_atomic_load(bar, __ATOMIC_ACQUIRE, __HIP_MEMORY_SCOPE_AGENT) < target){
      __builtin_amdgcn_s_sleep(8);
      if (++guard > (1<<17)) break;     // degrade to wrong-answer, never wedge the GPU
    }
  }
  __syncthreads();
}

// ======== BK=64 MFMA tile body, 256 thr, tile M=128 N=64, reg-prefetched ========
__device__ __forceinline__ void gemmBK64(
    const ushort_t* __restrict__ Ab, int lda, int m0,
    const ushort_t* __restrict__ Bb, int ldb, int n0,
    int Kbeg, int Kend, int mbound,
    ushort_t* As, ushort_t* Bs, int tid, f4 acc[4][2])
{
  const int r = tid>>3, c8 = (tid&7)*8;
  const int w = tid>>6, l = tid&63;
  const int wm = w>>1, wn = w&1, lr = l&15, lkq = (l>>4)*8;
  uint4 pa[4], pb[2];
  #pragma unroll
  for (int j=0;j<4;j++) pa[j] = *(const uint4*)(Ab + (size_t)(m0 + r + j*32)*lda + Kbeg + c8);
  #pragma unroll
  for (int j=0;j<2;j++) pb[j] = *(const uint4*)(Bb + (size_t)(n0 + r + j*32)*ldb + Kbeg + c8);
  for (int k0=Kbeg; k0<Kend; k0+=64){
    __syncthreads();
    #pragma unroll
    for (int j=0;j<4;j++) *(uint4*)(As + (r+j*32)*72 + c8) = pa[j];
    #pragma unroll
    for (int j=0;j<2;j++) *(uint4*)(Bs + (r+j*32)*72 + c8) = pb[j];
    __syncthreads();
    if (k0+64 < Kend){
      #pragma unroll
      for (int j=0;j<4;j++) pa[j] = *(const uint4*)(Ab + (size_t)(m0 + r + j*32)*lda + k0+64 + c8);
      #pragma unroll
      for (int j=0;j<2;j++) pb[j] = *(const uint4*)(Bb + (size_t)(n0 + r + j*32)*ldb + k0+64 + c8);
    }
    bf8 b00 = *(const bf8*)(Bs + (wn*32+lr)*72 + lkq);
    bf8 b01 = *(const bf8*)(Bs + (wn*32+lr)*72 + lkq + 32);
    bf8 b10 = *(const bf8*)(Bs + (wn*32+16+lr)*72 + lkq);
    bf8 b11 = *(const bf8*)(Bs + (wn*32+16+lr)*72 + lkq + 32);
    #pragma unroll
    for (int fm=0; fm<4; fm++){
      if (wm*64 + fm*16 < mbound){
        bf8 a0 = *(const bf8*)(As + (wm*64+fm*16+lr)*72 + lkq);
        bf8 a1 = *(const bf8*)(As + (wm*64+fm*16+lr)*72 + lkq + 32);
        acc[fm][0] = __builtin_amdgcn_mfma_f32_16x16x32_bf16(a0, b00, acc[fm][0], 0,0,0);
        acc[fm][0] = __builtin_amdgcn_mfma_f32_16x16x32_bf16(a1, b01, acc[fm][0], 0,0,0);
        acc[fm][1] = __builtin_amdgcn_mfma_f32_16x16x32_bf16(a0, b10, acc[fm][1], 0,0,0);
        acc[fm][1] = __builtin_amdgcn_mfma_f32_16x16x32_bf16(a1, b11, acc[fm][1], 0,0,0);
      }
    }
  }
}

// ---------------- sort + caps + decode_lengths + sort_ind + nact + bar reset ----------------
__global__ __launch_bounds__(128) void k_prep(const int* __restrict__ cap_len,
    const int* __restrict__ enc_caps, float* __restrict__ out,
    int* __restrict__ sort_i, int* __restrict__ decl_i, int* __restrict__ caps_i,
    int* __restrict__ nact_d, int* __restrict__ bar){
  __shared__ int lens[B];
  __shared__ int sind[B];
  __shared__ int s_dl[B];
  int t = threadIdx.x;
  if (t == 0) *bar = 0;
  lens[t] = cap_len[t];
  __syncthreads();
  int my = lens[t];
  int rank = 0;
  for (int j=0;j<B;j++){
    int lj = lens[j];
    if (lj > my || (lj == my && j < t)) rank++;
  }
  sind[rank] = t;
  __syncthreads();
  int src = sind[t];
  sort_i[t] = src;
  int dl = lens[src]-1;
  decl_i[t] = dl;
  s_dl[t] = dl;
  out[OFF_DECL+t] = (float)dl;
  out[OFF_SORT+t] = (float)src;
  for (int j=0;j<CAPLEN;j++){
    int v = enc_caps[src*CAPLEN+j];
    caps_i[t*CAPLEN+j] = v;
    out[OFF_CAPS + t*CAPLEN + j] = (float)v;
  }
  __syncthreads();
  if (t < TT){
    int cnt = 0;
    for (int b2=0;b2<B;b2++) cnt += (s_dl[b2] > t) ? 1 : 0;
    nact_d[t] = cnt;
  }
}

// ---------------- sorted enc -> bf16 ----------------
__global__ __launch_bounds__(256) void k_encb(const float* __restrict__ enc,
    const int* __restrict__ sort_i, ushort_t* __restrict__ encb){
  int row = blockIdx.x;
  int b = row/PP, p = row - b*PP;
  int sb = sort_i[b];
  const float4* s4 = (const float4*)(enc + ((size_t)sb*PP+p)*ENC);
  uint4* d4 = (uint4*)(encb + (size_t)row*ENC);
  int tid = threadIdx.x;
  float4 f0 = s4[tid*2], f1 = s4[tid*2+1];
  uint4 q;
  q.x = pack2(f0.x,f0.y); q.y = pack2(f0.z,f0.w);
  q.z = pack2(f1.x,f1.y); q.w = pack2(f1.z,f1.w);
  d4[tid] = q;
}

// ---------------- mean over P -> meanb bf16 ----------------
template<bool FULLT>
__global__ __launch_bounds__(256) void k_mean(const ushort_t* __restrict__ encb,
    const float* __restrict__ enc, const int* __restrict__ sort_i,
    ushort_t* __restrict__ meanb){
  int b = blockIdx.x, tid = threadIdx.x;
  int ch = tid*8;
  float a[8] = {};
  if (FULLT){
    const ushort_t* E = encb + (size_t)b*PP*ENC + ch;
    for (int p=0;p<PP;p++){
      uint4 q = *(const uint4*)(E + (size_t)p*ENC);
      float2 u0=b2x2(q.x),u1=b2x2(q.y),u2=b2x2(q.z),u3=b2x2(q.w);
      a[0]+=u0.x; a[1]+=u0.y; a[2]+=u1.x; a[3]+=u1.y;
      a[4]+=u2.x; a[5]+=u2.y; a[6]+=u3.x; a[7]+=u3.y;
    }
  } else {
    const float* E = enc + ((size_t)sort_i[b]*PP)*ENC + ch;
    for (int p=0;p<PP;p++){
      float4 f0 = *(const float4*)(E + (size_t)p*ENC);
      float4 f1 = *(const float4*)(E + (size_t)p*ENC + 4);
      a[0]+=f0.x; a[1]+=f0.y; a[2]+=f0.z; a[3]+=f0.w;
      a[4]+=f1.x; a[5]+=f1.y; a[6]+=f1.z; a[7]+=f1.w;
    }
  }
  const float inv = 1.0f/PP;
  uint4 q;
  q.x = pack2(a[0]*inv, a[1]*inv); q.y = pack2(a[2]*inv, a[3]*inv);
  q.z = pack2(a[4]*inv, a[5]*inv); q.w = pack2(a[6]*inv, a[7]*inv);
  *(uint4*)( (uint_t*)meanb + (size_t)b*(ENC/2) + tid*4 ) = q;
}

// ---------------- h0/c0 via MFMA ----------------
__global__ __launch_bounds__(256) void k_initg(const ushort_t* __restrict__ meanb,
    const float* __restrict__ Wh, const float* __restrict__ bh,
    const float* __restrict__ Wc, const float* __restrict__ bc,
    float* __restrict__ c, ushort_t* __restrict__ xb0){
  __shared__ __align__(16) ushort_t As[128*72];
  __shared__ __align__(16) ushort_t Bs[64*72];
  int tid = threadIdx.x;
  int n0 = blockIdx.x*64;
  const int r = tid>>3, c8 = (tid&7)*8;
  const int w = tid>>6, l = tid&63, wm = w>>1, wn = w&1, lr = l&15, lkq = (l>>4)*8;
  f4 acc[4][2] = {};
  for (int k0=0; k0<ENC; k0+=64){
    __syncthreads();
    #pragma unroll
    for (int j=0;j<4;j++){
      int rr = r + j*32;
      *(uint4*)(As + rr*72 + c8) = *(const uint4*)(meanb + (size_t)rr*ENC + k0 + c8);
    }
    #pragma unroll
    for (int j=0;j<2;j++){
      int rr = r + j*32;
      int n = n0 + rr;
      const float* src = (n < 512) ? (Wh + (size_t)n*ENC + k0 + c8)
                                   : (Wc + (size_t)(n-512)*ENC + k0 + c8);
      float4 f0 = *(const float4*)src, f1 = *(const float4*)(src+4);
      uint4 q; q.x=pack2(f0.x,f0.y); q.y=pack2(f0.z,f0.w); q.z=pack2(f1.x,f1.y); q.w=pack2(f1.z,f1.w);
      *(uint4*)(Bs + rr*72 + c8) = q;
    }
    __syncthreads();
    bf8 b00 = *(const bf8*)(Bs + (wn*32+lr)*72 + lkq);
    bf8 b01 = *(const bf8*)(Bs + (wn*32+lr)*72 + lkq + 32);
    bf8 b10 = *(const bf8*)(Bs + (wn*32+16+lr)*72 + lkq);
    bf8 b11 = *(const bf8*)(Bs + (wn*32+16+lr)*72 + lkq + 32);
    #pragma unroll
    for (int fm=0; fm<4; fm++){
      bf8 a0 = *(const bf8*)(As + (wm*64+fm*16+lr)*72 + lkq);
      bf8 a1 = *(const bf8*)(As + (wm*64+fm*16+lr)*72 + lkq + 32);
      acc[fm][0] = __builtin_amdgcn_mfma_f32_16x16x32_bf16(a0, b00, acc[fm][0], 0,0,0);
      acc[fm][0] = __builtin_amdgcn_mfma_f32_16x16x32_bf16(a1, b01, acc[fm][0], 0,0,0);
      acc[fm][1] = __builtin_amdgcn_mfma_f32_16x16x32_bf16(a0, b10, acc[fm][1], 0,0,0);
      acc[fm][1] = __builtin_amdgcn_mfma_f32_16x16x32_bf16(a1, b11, acc[fm][1], 0,0,0);
    }
  }
  #pragma unroll
  for (int fm=0; fm<4; fm++)
    #pragma unroll
    for (int fn=0; fn<2; fn++)
      #pragma unroll
      for (int rr=0; rr<4; rr++){
        int m = wm*64 + fm*16 + (l>>4)*4 + rr;
        int n = n0 + wn*32 + fn*16 + (l&15);
        float v = acc[fm][fn][rr];
        if (n < 512) xb0[(size_t)m*KP3 + n] = f2b(v + bh[n]);
        else         c[m*DEC + (n-512)] = v + bc[n-512];
      }
}

// ---------------- weight converters (one-time) ----------------
// INTERLEAVED gates layout: dst row n = unit j*4+g  <-  src row g*512+j
__global__ __launch_bounds__(256) void k_wkbi(const float* __restrict__ Whh,
    const float* __restrict__ Wih, uint_t* __restrict__ wkb_u){
  int n = blockIdx.x;
  int j = n>>2, g = n&3;
  int srow = g*512 + j;
  uint_t* dst = wkb_u + (size_t)n*(KP3/2);
  for (int u=threadIdx.x; u<KP3/2; u+=256){
    int k = 2*u; float a, bv;
    if (k < 512){ float2 v = *(const float2*)(Whh + (size_t)srow*512 + k); a=v.x; bv=v.y; }
    else if (k < 2860){ float2 v = *(const float2*)(Wih + (size_t)srow*2348 + (k-512)); a=v.x; bv=v.y; }
    else { a=0.f; bv=0.f; }
    dst[u] = pack2(a, bv);
  }
}
__global__ __launch_bounds__(256) void k_wcatb(const float* __restrict__ Wda,
    const float* __restrict__ Wfb, uint_t* __restrict__ wcat_u){
  int n = blockIdx.x;
  const float* src = (n < 512) ? (Wda + (size_t)n*512) : (Wfb + (size_t)(n-512)*512);
  float2 v = *(const float2*)(src + 2*threadIdx.x);
  wcat_u[(size_t)n*256 + threadIdx.x] = pack2(v.x, v.y);
}
__global__ __launch_bounds__(256) void k_wfcb(const float* __restrict__ Wfc,
    uint_t* __restrict__ wfc_u){
  int n = blockIdx.x;
  if (n < VV){
    float2 v = *(const float2*)(Wfc + (size_t)n*512 + 2*threadIdx.x);
    wfc_u[(size_t)n*256 + threadIdx.x] = pack2(v.x, v.y);
  } else wfc_u[(size_t)n*256 + threadIdx.x] = 0u;
}
__global__ __launch_bounds__(256) void k_xpad(uint_t* __restrict__ xb0_u,
    uint_t* __restrict__ xb1_u){
  uint_t* x = blockIdx.x ? xb1_u : xb0_u;
  for (int idx=threadIdx.x; idx<128*106; idx+=256){
    int rr = idx/106, cc = idx - rr*106;
    x[(size_t)rr*(KP3/2) + 1430 + cc] = 0u;
  }
}

// ---------------- one-time masked-zero writes for preds + alphas ----------------
__global__ __launch_bounds__(256) void k_zero(const int* __restrict__ decl_i,
    float* __restrict__ out){
  int blk = blockIdx.x;
  int b = blk/TT, t = blk - b*TT;
  if (t < decl_i[b]) return;
  float4 z = {0.f,0.f,0.f,0.f};
  float4* p = (float4*)(out + OFF_PRED + ((size_t)b*TT+t)*VV);
  for (int i=threadIdx.x; i<VV/4; i+=256) p[i] = z;
  size_t ao = (size_t)OFF_ALPH + ((size_t)b*TT+t)*PP;
  if (threadIdx.x < PP) out[ao + threadIdx.x] = 0.f;
}

// ---------------- one-time: att1 -> attb (MFMA; B staged from f32) ----------------
template<bool FULLT>
__global__ __launch_bounds__(256) void k_att1g(const ushort_t* __restrict__ encb,
    const float* __restrict__ enc, const int* __restrict__ sort_i,
    const float* __restrict__ Wea, const float* __restrict__ bea,
    ushort_t* __restrict__ attb){
  __shared__ __align__(16) ushort_t As[128*72];
  __shared__ __align__(16) ushort_t Bs[64*72];
  int tid = threadIdx.x;
  int m0 = blockIdx.x*128, n0 = blockIdx.y*64;
  const int r = tid>>3, c8 = (tid&7)*8;
  const int w = tid>>6, l = tid&63, wm = w>>1, wn = w&1, lr = l&15, lkq = (l>>4)*8;
  f4 acc[4][2] = {};
  for (int k0=0; k0<ENC; k0+=64){
    __syncthreads();
    #pragma unroll
    for (int j=0;j<4;j++){
      int rr = r + j*32, mg = m0 + rr;
      uint4 q;
      if (FULLT){
        q = *(const uint4*)(encb + (size_t)mg*ENC + k0 + c8);
      } else {
        int bq = mg/PP, p = mg - bq*PP;
        const float* src = enc + ((size_t)sort_i[bq]*PP + p)*ENC + k0 + c8;
        float4 f0 = *(const float4*)src, f1 = *(const float4*)(src+4);
        q.x=pack2(f0.x,f0.y); q.y=pack2(f0.z,f0.w); q.z=pack2(f1.x,f1.y); q.w=pack2(f1.z,f1.w);
      }
      *(uint4*)(As + rr*72 + c8) = q;
    }
    #pragma unroll
    for (int j=0;j<2;j++){
      int rr = r + j*32;
      const float* src = Wea + (size_t)(n0+rr)*ENC + k0 + c8;
      float4 f0 = *(const float4*)src, f1 = *(const float4*)(src+4);
      uint4 q; q.x=pack2(f0.x,f0.y); q.y=pack2(f0.z,f0.w); q.z=pack2(f1.x,f1.y); q.w=pack2(f1.z,f1.w);
      *(uint4*)(Bs + rr*72 + c8) = q;
    }
    __syncthreads();
    bf8 b00 = *(const bf8*)(Bs + (wn*32+lr)*72 + lkq);
    bf8 b01 = *(const bf8*)(Bs + (wn*32+lr)*72 + lkq + 32);
    bf8 b10 = *(const bf8*)(Bs + (wn*32+16+lr)*72 + lkq);
    bf8 b11 = *(const bf8*)(Bs + (wn*32+16+lr)*72 + lkq + 32);
    #pragma unroll
    for (int fm=0; fm<4; fm++){
      bf8 a0 = *(const bf8*)(As + (wm*64+fm*16+lr)*72 + lkq);
      bf8 a1 = *(const bf8*)(As + (wm*64+fm*16+lr)*72 + lkq + 32);
      acc[fm][0] = __builtin_amdgcn_mfma_f32_16x16x32_bf16(a0, b00, acc[fm][0], 0,0,0);
      acc[fm][0] = __builtin_amdgcn_mfma_f32_16x16x32_bf16(a1, b01, acc[fm][0], 0,0,0);
      acc[fm][1] = __builtin_amdgcn_mfma_f32_16x16x32_bf16(a0, b10, acc[fm][1], 0,0,0);
      acc[fm][1] = __builtin_amdgcn_mfma_f32_16x16x32_bf16(a1, b11, acc[fm][1], 0,0,0);
    }
  }
  #pragma unroll
  for (int fm=0; fm<4; fm++)
    #pragma unroll
    for (int fn=0; fn<2; fn++)
      #pragma unroll
      for (int rr=0; rr<4; rr++){
        int m = m0 + wm*64 + fm*16 + (l>>4)*4 + rr;
        int n = n0 + wn*32 + fn*16 + (l&15);
        attb[(size_t)m*ATTD + n] = f2b(acc[fm][fn][rr] + bea[n]);
      }
}

// ---------------- persistent step-loop kernel (3 phases / 3 barriers per step) ----------------
template<bool FULLT>
__global__ __launch_bounds__(256) void k_persist(
    ushort_t* __restrict__ xb0, ushort_t* __restrict__ xb1,
    const ushort_t* __restrict__ wkbi, const ushort_t* __restrict__ wcatb,
    const ushort_t* __restrict__ attb, const ushort_t* __restrict__ encb,
    const float* __restrict__ enc, const float* __restrict__ embedding,
    const float* __restrict__ bda, const float* __restrict__ bfb,
    const float* __restrict__ wfa, const float* __restrict__ bfa,
    const float* __restrict__ b_ih, const float* __restrict__ b_hh,
    const int* __restrict__ sort_i, const int* __restrict__ decl_i,
    const int* __restrict__ caps_i, const int* __restrict__ nact_d,
    float* __restrict__ att2s, float* __restrict__ gate,
    float* __restrict__ c, ushort_t* __restrict__ hnball,
    float* __restrict__ out, int* bar)
{
  __shared__ __align__(16) ushort_t As[128*72];
  __shared__ __align__(16) ushort_t Bs[64*72];
  __shared__ float s_bias[32];
  int blk = blockIdx.x, tid = threadIdx.x;
  int bno = 0;
  const int w = tid>>6, l = tid&63, wm = w>>1, wn = w&1;

  for (int t=0; t<TT; ++t){
    int mb = nact_d[t];
    ushort_t* xbc = (t&1) ? xb1 : xb0;     // current-step input matrix
    ushort_t* xbn = (t&1) ? xb0 : xb1;     // next-step input matrix
    uint_t* xbc_u = (uint_t*)xbc;
    // ===== phase 1: att2+gate GEMM (blk<40)  |  emb -> xbc (40<=blk<104) =====
    if (blk < 40){
      f4 acc[4][2] = {};
      gemmBK64(xbc, KP3, 0, wcatb, 512, blk*64, 0, 512, mb, As, Bs, tid, acc);
      #pragma unroll
      for (int fm=0; fm<4; fm++)
        #pragma unroll
        for (int fn=0; fn<2; fn++)
          #pragma unroll
          for (int rr=0; rr<4; rr++){
            int m = wm*64 + fm*16 + (l>>4)*4 + rr;
            int n = blk*64 + wn*32 + fn*16 + (l&15);
            float v = acc[fm][fn][rr];
            if (n < 512) att2s[m*512+n] = v + bda[n];
            else         gate[m*2048 + (n-512)] = sigf(v + bfb[n-512]);
          }
    } else if (blk < 104){
      int b = (blk-40)*2 + (tid>>7);
      int tok = caps_i[b*CAPLEN+t];
      for (int u=(tid&127); u<150; u+=128){
        float2 e = *(const float2*)(embedding + (size_t)tok*EMB + 2*u);
        xbc_u[b*(KP3/2) + 256 + u] = pack2(e.x, e.y);
      }
    }
    gbar(bar, (++bno)*NBLK);
    // ===== phase 2: score + softmax + alpha + awe*gate -> xbc (blk = b) =====
    {
      int b = blk;
      if (t < decl_i[b]){
        float* sf   = (float*)As;
        float* s_a2 = sf;          float* s_w  = sf+512;
        float* s_sc = sf+1024;     float* s_al = sf+1232;
        float* s_r1 = sf+1440;     float* s_r2 = sf+1448;
        s_a2[tid] = att2s[b*512+tid]; s_a2[256+tid] = att2s[b*512+256+tid];
        s_w[tid]  = wfa[tid];         s_w[256+tid]  = wfa[256+tid];
        __syncthreads();
        int wid = tid>>6, lane = tid&63;
        float b0 = bfa[0];
        for (int p=wid; p<PP; p+=4){
          uint4 q = ((const uint4*)(attb + ((size_t)b*PP + p)*ATTD))[lane];
          int j = lane*8;
          float2 x0=b2x2(q.x), x1=b2x2(q.y), x2=b2x2(q.z), x3=b2x2(q.w);
          float s = fmaxf(x0.x+s_a2[j+0],0.f)*s_w[j+0] + fmaxf(x0.y+s_a2[j+1],0.f)*s_w[j+1]
                  + fmaxf(x1.x+s_a2[j+2],0.f)*s_w[j+2] + fmaxf(x1.y+s_a2[j+3],0.f)*s_w[j+3]
                  + fmaxf(x2.x+s_a2[j+4],0.f)*s_w[j+4] + fmaxf(x2.y+s_a2[j+5],0.f)*s_w[j+5]
                  + fmaxf(x3.x+s_a2[j+6],0.f)*s_w[j+6] + fmaxf(x3.y+s_a2[j+7],0.f)*s_w[j+7];
          #pragma unroll
          for (int off=32;off;off>>=1) s += __shfl_down(s,off);
          if (lane==0) s_sc[p] = s + b0;
        }
        __syncthreads();
        float sc = (tid<PP) ? s_sc[tid] : -1e30f;
        float mx = sc;
        #pragma unroll
        for (int off=32;off;off>>=1) mx = fmaxf(mx, __shfl_down(mx,off));
        if (lane==0) s_r1[wid] = mx;
        __syncthreads();
        mx = fmaxf(fmaxf(s_r1[0],s_r1[1]), fmaxf(s_r1[2],s_r1[3]));
        float e = (tid<PP) ? expf(sc-mx) : 0.f;
        float sm = e;
        #pragma unroll
        for (int off=32;off;off>>=1) sm += __shfl_down(sm,off);
        if (lane==0) s_r2[wid] = sm;
        __syncthreads();
        float inv = 1.f/(s_r2[0]+s_r2[1]+s_r2[2]+s_r2[3]);
        if (tid<PP){
          float al = e*inv;
          s_al[tid] = al;
          out[(size_t)OFF_ALPH + ((size_t)b*TT+t)*PP + tid] = al;
        }
        __syncthreads();
        int ch = tid*8;
        float a0=0.f,a1=0.f,a2=0.f,a3=0.f,a4=0.f,a5=0.f,a6=0.f,a7=0.f;
        if (FULLT){
          const ushort_t* E = encb + (size_t)b*PP*ENC + ch;
          #pragma unroll 2
          for (int p=0;p<PP;p++){
            uint4 q = *(const uint4*)(E + (size_t)p*ENC);
            float al = s_al[p];
            float2 u0=b2x2(q.x),u1=b2x2(q.y),u2=b2x2(q.z),u3=b2x2(q.w);
            a0+=al*u0.x; a1+=al*u0.y; a2+=al*u1.x; a3+=al*u1.y;
            a4+=al*u2.x; a5+=al*u2.y; a6+=al*u3.x; a7+=al*u3.y;
          }
        } else {
          const float* E = enc + ((size_t)sort_i[b]*PP)*ENC + ch;
          #pragma unroll 2
          for (int p=0;p<PP;p++){
            float4 f0 = *(const float4*)(E + (size_t)p*ENC);
            float4 f1 = *(const float4*)(E + (size_t)p*ENC + 4);
            float al = s_al[p];
            a0+=al*f0.x; a1+=al*f0.y; a2+=al*f0.z; a3+=al*f0.w;
            a4+=al*f1.x; a5+=al*f1.y; a6+=al*f1.z; a7+=al*f1.w;
          }
        }
        float4 g0 = *(const float4*)(gate + b*2048 + ch);
        float4 g1 = *(const float4*)(gate + b*2048 + ch + 4);
        uint2 w0, w1;
        w0.x = pack2(a0*g0.x, a1*g0.y); w0.y = pack2(a2*g0.z, a3*g0.w);
        w1.x = pack2(a4*g1.x, a5*g1.y); w1.y = pack2(a6*g1.z, a7*g1.w);
        *(uint2*)(xbc_u + b*(KP3/2) + 406 + tid*4)     = w0;
        *(uint2*)(xbc_u + b*(KP3/2) + 406 + tid*4 + 2) = w1;
      }
    }
    gbar(bar, (++bno)*NBLK);
    // ===== phase 3: gates GEMM full-K (N=32 tile, interleaved) + fused LSTM cell =====
    if (blk < 64){
      int n0q = blk*32;
      if (tid < 32){
        int g = tid&3, j = blk*8 + (tid>>2);
        s_bias[tid] = b_ih[g*512+j] + b_hh[g*512+j];
      }
      const int r = tid>>3, c8 = (tid&7)*8;
      const int lr = l&15, lkq = (l>>4)*8;
      f4 acc[2][2] = {};
      uint4 pa[4], pb1;
      #pragma unroll
      for (int j=0;j<4;j++) pa[j] = *(const uint4*)(xbc + (size_t)(r + j*32)*KP3 + c8);
      pb1 = *(const uint4*)(wkbi + (size_t)(n0q + r)*KP3 + c8);
      for (int k0=0; k0<KUSE; k0+=64){
        __syncthreads();
        #pragma unroll
        for (int j=0;j<4;j++) *(uint4*)(As + (r+j*32)*72 + c8) = pa[j];
        *(uint4*)(Bs + r*72 + c8) = pb1;
        __syncthreads();
        if (k0+64 < KUSE){
          #pragma unroll
          for (int j=0;j<4;j++) pa[j] = *(const uint4*)(xbc + (size_t)(r + j*32)*KP3 + k0+64 + c8);
          pb1 = *(const uint4*)(wkbi + (size_t)(n0q + r)*KP3 + k0+64 + c8);
        }
        bf8 b00 = *(const bf8*)(Bs + lr*72 + lkq);
        bf8 b01 = *(const bf8*)(Bs + lr*72 + lkq + 32);
        bf8 b10 = *(const bf8*)(Bs + (16+lr)*72 + lkq);
        bf8 b11 = *(const bf8*)(Bs + (16+lr)*72 + lkq + 32);
        #pragma unroll
        for (int fm=0; fm<2; fm++){
          if (w*32 + fm*16 < mb){
            bf8 a0 = *(const bf8*)(As + (w*32+fm*16+lr)*72 + lkq);
            bf8 a1 = *(const bf8*)(As + (w*32+fm*16+lr)*72 + lkq + 32);
            acc[fm][0] = __builtin_amdgcn_mfma_f32_16x16x32_bf16(a0, b00, acc[fm][0], 0,0,0);
            acc[fm][0] = __builtin_amdgcn_mfma_f32_16x16x32_bf16(a1, b01, acc[fm][0], 0,0,0);
            acc[fm][1] = __builtin_amdgcn_mfma_f32_16x16x32_bf16(a0, b10, acc[fm][1], 0,0,0);
            acc[fm][1] = __builtin_amdgcn_mfma_f32_16x16x32_bf16(a1, b11, acc[fm][1], 0,0,0);
          }
        }
      }
      __syncthreads();
      float* sacc = (float*)As;           // 128 x 33 f32 = 16.9 KB, fits in As
      #pragma unroll
      for (int fm=0; fm<2; fm++)
        #pragma unroll
        for (int fn=0; fn<2; fn++)
          #pragma unroll
          for (int rr=0; rr<4; rr++){
            int m = w*32 + fm*16 + (l>>4)*4 + rr;
            int nn = fn*16 + (l&15);
            sacc[m*33+nn] = acc[fm][fn][rr];
          }
      __syncthreads();
      #pragma unroll
      for (int q=0;q<4;q++){
        int idx = q*256 + tid;
        int m = idx>>3, u = idx&7;
        int j = blk*8 + u;
        float gi = sacc[m*33 + u*4+0] + s_bias[u*4+0];
        float gf = sacc[m*33 + u*4+1] + s_bias[u*4+1];
        float gg = sacc[m*33 + u*4+2] + s_bias[u*4+2];
        float go = sacc[m*33 + u*4+3] + s_bias[u*4+3];
        float cn = sigf(gf)*c[m*DEC+j] + sigf(gi)*tanhf(gg);
        float hn = sigf(go)*tanhf(cn);
        hnball[((size_t)t*B + m)*DEC + j] = f2b(hn);
        bool act = t < decl_i[m];
        if (act) c[m*DEC+j] = cn;
        xbn[(size_t)m*KP3 + j] = act ? f2b(hn) : xbc[(size_t)m*KP3 + j];
      }
    }
    gbar(bar, (++bno)*NBLK);
  }
}

// ---------------- deferred: preds GEMM over all steps ----------------
__global__ __launch_bounds__(256) void k_predall(const ushort_t* __restrict__ hnball,
    const ushort_t* __restrict__ wfcb, const float* __restrict__ b_fc,
    const int* __restrict__ nact_d, float* __restrict__ out){
  __shared__ __align__(16) ushort_t As[128*72];
  __shared__ __align__(16) ushort_t Bs[64*72];
  int tid = threadIdx.x;
  int t = blockIdx.y;
  int n0 = blockIdx.x*64;
  int mb = nact_d[t];
  f4 acc[4][2] = {};
  gemmBK64(hnball + (size_t)t*B*DEC, DEC, 0, wfcb, DEC, n0, 0, DEC, mb, As, Bs, tid, acc);
  int w = tid>>6, l = tid&63, wm = w>>1, wn = w&1;
  #pragma unroll
  for (int fm=0; fm<4; fm++)
    #pragma unroll
    for (int fn=0; fn<2; fn++)
      #pragma unroll
      for (int rr=0; rr<4; rr++){
        int m = wm*64 + fm*16 + (l>>4)*4 + rr;
        int n = n0 + wn*32 + fn*16 + (l&15);
        if (m < mb && n < VV)
          out[OFF_PRED + ((size_t)m*TT + t)*VV + n] = acc[fm][fn][rr] + b_fc[n];
      }
}

extern "C" void kernel_launch(void* const* d_in, const int* in_sizes, int n_in,
                              void* d_out, int out_size, void* d_ws, size_t ws_size,
                              hipStream_t stream){
  const float* enc       = (const float*)d_in[0];
  const int*   caps_in   = (const int*)d_in[1];
  const int*   caplen    = (const int*)d_in[2];
  const float* W_enc_att = (const float*)d_in[3];
  const float* b_enc_att = (const float*)d_in[4];
  const float* W_dec_att = (const float*)d_in[5];
  const float* b_dec_att = (const float*)d_in[6];
  const float* w_full_att= (const float*)d_in[7];
  const float* b_full_att= (const float*)d_in[8];
  const float* embedding = (const float*)d_in[9];
  const float* W_ih      = (const float*)d_in[10];
  const float* b_ih      = (const float*)d_in[11];
  const float* W_hh      = (const float*)d_in[12];
  const float* b_hh      = (const float*)d_in[13];
  const float* W_init_h  = (const float*)d_in[14];
  const float* b_init_h  = (const float*)d_in[15];
  const float* W_init_c  = (const float*)d_in[16];
  const float* b_init_c  = (const float*)d_in[17];
  const float* W_fbeta   = (const float*)d_in[18];
  const float* b_fbeta   = (const float*)d_in[19];
  const float* W_fc      = (const float*)d_in[20];
  const float* b_fc      = (const float*)d_in[21];
  float* out = (float*)d_out;

  char* base = (char*)d_ws;
  size_t off = 0;
  auto AL = [&](size_t bytes)->void*{ void* p = base + off; off = (off + bytes + 15) & ~15ull; return p; };

  bool FULL = ws_size >= 168000000ull;

  float* c      = (float*)AL(65536*4);
  float* att2s  = (float*)AL(65536*4);
  float* gate   = (float*)AL(262144*4);
  ushort_t* meanb  = (ushort_t*)AL(262144*2);       // 128 x 2048
  ushort_t* xb0    = (ushort_t*)AL(393216*2);       // 128 x 3072
  ushort_t* xb1    = (ushort_t*)AL(393216*2);       // 128 x 3072
  ushort_t* wkbi   = (ushort_t*)AL((size_t)6291456*2);   // 2048 x 3072 (interleaved)
  ushort_t* wcatb  = (ushort_t*)AL(1310720*2);      // 2560 x 512
  ushort_t* wfcb   = (ushort_t*)AL(5177344*2);      // 10112 x 512
  ushort_t* hnball = (ushort_t*)AL(3276800*2);      // 50 x 128 x 512
  ushort_t* attb   = (ushort_t*)AL((size_t)12845056*2);  // 25088 x 512
  int* sort_i = (int*)AL(128*4);
  int* decl_i = (int*)AL(128*4);
  int* nact_d = (int*)AL(64*4);
  int* caps_i = (int*)AL(6528*4);
  int* bar    = (int*)AL(64*4);
  ushort_t* encb = FULL ? (ushort_t*)AL((size_t)51380224*2) : nullptr;   // 25088 x 2048

  k_prep<<<1,128,0,stream>>>(caplen, caps_in, out, sort_i, decl_i, caps_i, nact_d, bar);
  if (FULL) k_encb<<<25088,256,0,stream>>>(enc, sort_i, encb);
  if (FULL) k_mean<true><<<128,256,0,stream>>>(encb, enc, sort_i, meanb);
  else      k_mean<false><<<128,256,0,stream>>>(encb, enc, sort_i, meanb);
  k_initg<<<16,256,0,stream>>>(meanb, W_init_h, b_init_h, W_init_c, b_init_c, c, xb0);
  k_wkbi<<<2048,256,0,stream>>>(W_hh, W_ih, (uint_t*)wkbi);
  k_wcatb<<<2560,256,0,stream>>>(W_dec_att, W_fbeta, (uint_t*)wcatb);
  k_wfcb<<<NPPAD,256,0,stream>>>(W_fc, (uint_t*)wfcb);
  k_xpad<<<2,256,0,stream>>>((uint_t*)xb0, (uint_t*)xb1);
  k_zero<<<6400,256,0,stream>>>(decl_i, out);
  if (FULL) k_att1g<true><<<dim3(196,8),256,0,stream>>>(encb, enc, sort_i, W_enc_att, b_enc_att, attb);
  else      k_att1g<false><<<dim3(196,8),256,0,stream>>>(encb, enc, sort_i, W_enc_att, b_enc_att, attb);

  if (FULL)
    k_persist<true><<<NBLK,256,0,stream>>>(xb0, xb1, wkbi, wcatb, attb, encb, enc, embedding,
        b_dec_att, b_fbeta, w_full_att, b_full_att, b_ih, b_hh,
        sort_i, decl_i, caps_i, nact_d, att2s, gate, c, hnball, out, bar);
  else
    k_persist<false><<<NBLK,256,0,stream>>>(xb0, xb1, wkbi, wcatb, attb, encb, enc, embedding,
        b_dec_att, b_fbeta, w_full_att, b_full_att, b_ih, b_hh,
        sort_i, decl_i, caps_i, nact_d, att2s, gate, c, hnball, out, bar);

  k_predall<<<dim3(158,TT),256,0,stream>>>(hnball, wfcb, b_fc, nact_d, out);
}

// Round 8
// 10402.695 us; speedup vs baseline: 1.2743x; 1.2743x over previous
//
#include <hip/hip_runtime.h>
#include <math.h>

#define B 128
#define PP 196
#define ENC 2048
#define DEC 512
#define ATTD 512
#define EMB 300
#define VV 10000
#define CAPLEN 51
#define TT 50
#define KP3 3072           // padded K: 512(h)+300(emb)+2048(gawe)+212 pad (zeroed)
#define NPPAD 10112        // pred N padded to 158*64
#define NBLK 128           // persistent grid

static const long long OFF_PRED = 0LL;
static const long long OFF_CAPS = 64000000LL;
static const long long OFF_DECL = 64006528LL;
static const long long OFF_ALPH = 64006656LL;
static const long long OFF_SORT = 65261056LL;

typedef unsigned short ushort_t;
typedef unsigned int uint_t;
typedef short bf8 __attribute__((ext_vector_type(8)));
typedef float f4 __attribute__((ext_vector_type(4)));

__device__ __forceinline__ float sigf(float x){ return 1.f/(1.f+expf(-x)); }
__device__ __forceinline__ float b2f(ushort_t u){
  union{uint_t i; float f;} v; v.i = ((uint_t)u)<<16; return v.f;
}
__device__ __forceinline__ ushort_t f2b(float f){
  union{float f; uint_t i;} v; v.f = f;
  uint_t r = v.i + 0x7fffu + ((v.i>>16)&1u);
  return (ushort_t)(r>>16);
}
__device__ __forceinline__ uint_t pack2(float lo, float hi){
  return (uint_t)f2b(lo) | ((uint_t)f2b(hi)<<16);
}
__device__ __forceinline__ float2 b2x2(uint_t u){
  union{uint_t i; float f;} a,b; a.i = u<<16; b.i = u & 0xffff0000u;
  return make_float2(a.f, b.f);
}

// ---- flag-array grid barrier: per-block RELEASE flag, block0 aggregates with
// ---- RELAXED parallel polls, single release word, one ACQUIRE fence on exit.
__device__ __forceinline__ void gbar2(int* flags, int* rel, int e, int blk, int tid){
  __syncthreads();
  if (blk == 0){
    if (tid >= 1 && tid < NBLK){
      int guard = 0;
      while (__hip_atomic_load(flags + tid*32, __ATOMIC_RELAXED, __HIP_MEMORY_SCOPE_AGENT) < e){
        __builtin_amdgcn_s_sleep(1);
        if (++guard > (1<<16)) break;          // fail-safe: never wedge
      }
    }
    __syncthreads();
    __builtin_amdgcn_fence(__ATOMIC_ACQUIRE, "agent");
    if (tid == 0)
      __hip_atomic_store(rel, e, __ATOMIC_RELEASE, __HIP_MEMORY_SCOPE_AGENT);
  } else {
    if (tid == 0){
      __hip_atomic_store(flags + blk*32, e, __ATOMIC_RELEASE, __HIP_MEMORY_SCOPE_AGENT);
      int guard = 0;
      while (__hip_atomic_load(rel, __ATOMIC_RELAXED, __HIP_MEMORY_SCOPE_AGENT) < e){
        __builtin_amdgcn_s_sleep(4);
        if (++guard > (1<<16)) break;
      }
    }
  }
  __syncthreads();
  __builtin_amdgcn_fence(__ATOMIC_ACQUIRE, "agent");
}

// ======== BK=64 MFMA tile body, 256 thr, tile M=128 N=64, reg-prefetched ========
__device__ __forceinline__ void gemmBK64(
    const ushort_t* __restrict__ Ab, int lda, int m0,
    const ushort_t* __restrict__ Bb, int ldb, int n0,
    int Kbeg, int Kend, int mbound,
    ushort_t* As, ushort_t* Bs, int tid, f4 acc[4][2])
{
  const int r = tid>>3, c8 = (tid&7)*8;
  const int w = tid>>6, l = tid&63;
  const int wm = w>>1, wn = w&1, lr = l&15, lkq = (l>>4)*8;
  uint4 pa[4], pb[2];
  #pragma unroll
  for (int j=0;j<4;j++) pa[j] = *(const uint4*)(Ab + (size_t)(m0 + r + j*32)*lda + Kbeg + c8);
  #pragma unroll
  for (int j=0;j<2;j++) pb[j] = *(const uint4*)(Bb + (size_t)(n0 + r + j*32)*ldb + Kbeg + c8);
  for (int k0=Kbeg; k0<Kend; k0+=64){
    __syncthreads();
    #pragma unroll
    for (int j=0;j<4;j++) *(uint4*)(As + (r+j*32)*72 + c8) = pa[j];
    #pragma unroll
    for (int j=0;j<2;j++) *(uint4*)(Bs + (r+j*32)*72 + c8) = pb[j];
    __syncthreads();
    if (k0+64 < Kend){
      #pragma unroll
      for (int j=0;j<4;j++) pa[j] = *(const uint4*)(Ab + (size_t)(m0 + r + j*32)*lda + k0+64 + c8);
      #pragma unroll
      for (int j=0;j<2;j++) pb[j] = *(const uint4*)(Bb + (size_t)(n0 + r + j*32)*ldb + k0+64 + c8);
    }
    bf8 b00 = *(const bf8*)(Bs + (wn*32+lr)*72 + lkq);
    bf8 b01 = *(const bf8*)(Bs + (wn*32+lr)*72 + lkq + 32);
    bf8 b10 = *(const bf8*)(Bs + (wn*32+16+lr)*72 + lkq);
    bf8 b11 = *(const bf8*)(Bs + (wn*32+16+lr)*72 + lkq + 32);
    #pragma unroll
    for (int fm=0; fm<4; fm++){
      if (wm*64 + fm*16 < mbound){
        bf8 a0 = *(const bf8*)(As + (wm*64+fm*16+lr)*72 + lkq);
        bf8 a1 = *(const bf8*)(As + (wm*64+fm*16+lr)*72 + lkq + 32);
        acc[fm][0] = __builtin_amdgcn_mfma_f32_16x16x32_bf16(a0, b00, acc[fm][0], 0,0,0);
        acc[fm][0] = __builtin_amdgcn_mfma_f32_16x16x32_bf16(a1, b01, acc[fm][0], 0,0,0);
        acc[fm][1] = __builtin_amdgcn_mfma_f32_16x16x32_bf16(a0, b10, acc[fm][1], 0,0,0);
        acc[fm][1] = __builtin_amdgcn_mfma_f32_16x16x32_bf16(a1, b11, acc[fm][1], 0,0,0);
      }
    }
  }
}

// ---------------- sort + caps + decode_lengths + sort_ind + nact + flag reset ----------------
__global__ __launch_bounds__(128) void k_prep(const int* __restrict__ cap_len,
    const int* __restrict__ enc_caps, float* __restrict__ out,
    int* __restrict__ sort_i, int* __restrict__ decl_i, int* __restrict__ caps_i,
    int* __restrict__ nact_d, int* __restrict__ flags){
  __shared__ int lens[B];
  __shared__ int sind[B];
  __shared__ int s_dl[B];
  int t = threadIdx.x;
  for (int idx=t; idx<NBLK*32+32; idx+=128) flags[idx] = 0;   // flags + rel word
  lens[t] = cap_len[t];
  __syncthreads();
  int my = lens[t];
  int rank = 0;
  for (int j=0;j<B;j++){
    int lj = lens[j];
    if (lj > my || (lj == my && j < t)) rank++;
  }
  sind[rank] = t;
  __syncthreads();
  int src = sind[t];
  sort_i[t] = src;
  int dl = lens[src]-1;
  decl_i[t] = dl;
  s_dl[t] = dl;
  out[OFF_DECL+t] = (float)dl;
  out[OFF_SORT+t] = (float)src;
  for (int j=0;j<CAPLEN;j++){
    int v = enc_caps[src*CAPLEN+j];
    caps_i[t*CAPLEN+j] = v;
    out[OFF_CAPS + t*CAPLEN + j] = (float)v;
  }
  __syncthreads();
  if (t < TT){
    int cnt = 0;
    for (int b2=0;b2<B;b2++) cnt += (s_dl[b2] > t) ? 1 : 0;
    nact_d[t] = cnt;
  }
}

// ---------------- sorted enc -> bf16 ----------------
__global__ __launch_bounds__(256) void k_encb(const float* __restrict__ enc,
    const int* __restrict__ sort_i, ushort_t* __restrict__ encb){
  int row = blockIdx.x;
  int b = row/PP, p = row - b*PP;
  int sb = sort_i[b];
  const float4* s4 = (const float4*)(enc + ((size_t)sb*PP+p)*ENC);
  uint4* d4 = (uint4*)(encb + (size_t)row*ENC);
  int tid = threadIdx.x;
  float4 f0 = s4[tid*2], f1 = s4[tid*2+1];
  uint4 q;
  q.x = pack2(f0.x,f0.y); q.y = pack2(f0.z,f0.w);
  q.z = pack2(f1.x,f1.y); q.w = pack2(f1.z,f1.w);
  d4[tid] = q;
}

// ---------------- mean over P -> meanb bf16 ----------------
template<bool FULLT>
__global__ __launch_bounds__(256) void k_mean(const ushort_t* __restrict__ encb,
    const float* __restrict__ enc, const int* __restrict__ sort_i,
    ushort_t* __restrict__ meanb){
  int b = blockIdx.x, tid = threadIdx.x;
  int ch = tid*8;
  float a[8] = {};
  if (FULLT){
    const ushort_t* E = encb + (size_t)b*PP*ENC + ch;
    for (int p=0;p<PP;p++){
      uint4 q = *(const uint4*)(E + (size_t)p*ENC);
      float2 u0=b2x2(q.x),u1=b2x2(q.y),u2=b2x2(q.z),u3=b2x2(q.w);
      a[0]+=u0.x; a[1]+=u0.y; a[2]+=u1.x; a[3]+=u1.y;
      a[4]+=u2.x; a[5]+=u2.y; a[6]+=u3.x; a[7]+=u3.y;
    }
  } else {
    const float* E = enc + ((size_t)sort_i[b]*PP)*ENC + ch;
    for (int p=0;p<PP;p++){
      float4 f0 = *(const float4*)(E + (size_t)p*ENC);
      float4 f1 = *(const float4*)(E + (size_t)p*ENC + 4);
      a[0]+=f0.x; a[1]+=f0.y; a[2]+=f0.z; a[3]+=f0.w;
      a[4]+=f1.x; a[5]+=f1.y; a[6]+=f1.z; a[7]+=f1.w;
    }
  }
  const float inv = 1.0f/PP;
  uint4 q;
  q.x = pack2(a[0]*inv, a[1]*inv); q.y = pack2(a[2]*inv, a[3]*inv);
  q.z = pack2(a[4]*inv, a[5]*inv); q.w = pack2(a[6]*inv, a[7]*inv);
  *(uint4*)( (uint_t*)meanb + (size_t)b*(ENC/2) + tid*4 ) = q;
}

// ---------------- h0/c0 via MFMA ----------------
__global__ __launch_bounds__(256) void k_initg(const ushort_t* __restrict__ meanb,
    const float* __restrict__ Wh, const float* __restrict__ bh,
    const float* __restrict__ Wc, const float* __restrict__ bc,
    float* __restrict__ c, ushort_t* __restrict__ xb0){
  __shared__ __align__(16) ushort_t As[128*72];
  __shared__ __align__(16) ushort_t Bs[64*72];
  int tid = threadIdx.x;
  int n0 = blockIdx.x*64;
  const int r = tid>>3, c8 = (tid&7)*8;
  const int w = tid>>6, l = tid&63, wm = w>>1, wn = w&1, lr = l&15, lkq = (l>>4)*8;
  f4 acc[4][2] = {};
  for (int k0=0; k0<ENC; k0+=64){
    __syncthreads();
    #pragma unroll
    for (int j=0;j<4;j++){
      int rr = r + j*32;
      *(uint4*)(As + rr*72 + c8) = *(const uint4*)(meanb + (size_t)rr*ENC + k0 + c8);
    }
    #pragma unroll
    for (int j=0;j<2;j++){
      int rr = r + j*32;
      int n = n0 + rr;
      const float* src = (n < 512) ? (Wh + (size_t)n*ENC + k0 + c8)
                                   : (Wc + (size_t)(n-512)*ENC + k0 + c8);
      float4 f0 = *(const float4*)src, f1 = *(const float4*)(src+4);
      uint4 q; q.x=pack2(f0.x,f0.y); q.y=pack2(f0.z,f0.w); q.z=pack2(f1.x,f1.y); q.w=pack2(f1.z,f1.w);
      *(uint4*)(Bs + rr*72 + c8) = q;
    }
    __syncthreads();
    bf8 b00 = *(const bf8*)(Bs + (wn*32+lr)*72 + lkq);
    bf8 b01 = *(const bf8*)(Bs + (wn*32+lr)*72 + lkq + 32);
    bf8 b10 = *(const bf8*)(Bs + (wn*32+16+lr)*72 + lkq);
    bf8 b11 = *(const bf8*)(Bs + (wn*32+16+lr)*72 + lkq + 32);
    #pragma unroll
    for (int fm=0; fm<4; fm++){
      bf8 a0 = *(const bf8*)(As + (wm*64+fm*16+lr)*72 + lkq);
      bf8 a1 = *(const bf8*)(As + (wm*64+fm*16+lr)*72 + lkq + 32);
      acc[fm][0] = __builtin_amdgcn_mfma_f32_16x16x32_bf16(a0, b00, acc[fm][0], 0,0,0);
      acc[fm][0] = __builtin_amdgcn_mfma_f32_16x16x32_bf16(a1, b01, acc[fm][0], 0,0,0);
      acc[fm][1] = __builtin_amdgcn_mfma_f32_16x16x32_bf16(a0, b10, acc[fm][1], 0,0,0);
      acc[fm][1] = __builtin_amdgcn_mfma_f32_16x16x32_bf16(a1, b11, acc[fm][1], 0,0,0);
    }
  }
  #pragma unroll
  for (int fm=0; fm<4; fm++)
    #pragma unroll
    for (int fn=0; fn<2; fn++)
      #pragma unroll
      for (int rr=0; rr<4; rr++){
        int m = wm*64 + fm*16 + (l>>4)*4 + rr;
        int n = n0 + wn*32 + fn*16 + (l&15);
        float v = acc[fm][fn][rr];
        if (n < 512) xb0[(size_t)m*KP3 + n] = f2b(v + bh[n]);
        else         c[m*DEC + (n-512)] = v + bc[n-512];
      }
}

// ---------------- weight converters (one-time) ----------------
// INTERLEAVED gates layout: dst row n = unit j*4+g  <-  src row g*512+j
__global__ __launch_bounds__(256) void k_wkbi(const float* __restrict__ Whh,
    const float* __restrict__ Wih, uint_t* __restrict__ wkb_u){
  int n = blockIdx.x;
  int j = n>>2, g = n&3;
  int srow = g*512 + j;
  uint_t* dst = wkb_u + (size_t)n*(KP3/2);
  for (int u=threadIdx.x; u<KP3/2; u+=256){
    int k = 2*u; float a, bv;
    if (k < 512){ float2 v = *(const float2*)(Whh + (size_t)srow*512 + k); a=v.x; bv=v.y; }
    else if (k < 2860){ float2 v = *(const float2*)(Wih + (size_t)srow*2348 + (k-512)); a=v.x; bv=v.y; }
    else { a=0.f; bv=0.f; }
    dst[u] = pack2(a, bv);
  }
}
__global__ __launch_bounds__(256) void k_wcatb(const float* __restrict__ Wda,
    const float* __restrict__ Wfb, uint_t* __restrict__ wcat_u){
  int n = blockIdx.x;
  const float* src = (n < 512) ? (Wda + (size_t)n*512) : (Wfb + (size_t)(n-512)*512);
  float2 v = *(const float2*)(src + 2*threadIdx.x);
  wcat_u[(size_t)n*256 + threadIdx.x] = pack2(v.x, v.y);
}
__global__ __launch_bounds__(256) void k_wfcb(const float* __restrict__ Wfc,
    uint_t* __restrict__ wfc_u){
  int n = blockIdx.x;
  if (n < VV){
    float2 v = *(const float2*)(Wfc + (size_t)n*512 + 2*threadIdx.x);
    wfc_u[(size_t)n*256 + threadIdx.x] = pack2(v.x, v.y);
  } else wfc_u[(size_t)n*256 + threadIdx.x] = 0u;
}
// interleaved combined LSTM bias: biasI[j*4+g] = b_ih[g*512+j] + b_hh[g*512+j]
__global__ __launch_bounds__(256) void k_biasb(const float* __restrict__ b_ih,
    const float* __restrict__ b_hh, float* __restrict__ biasI){
  int n = blockIdx.x*256 + threadIdx.x;
  int j = n>>2, g = n&3;
  biasI[n] = b_ih[g*512+j] + b_hh[g*512+j];
}
__global__ __launch_bounds__(256) void k_xpad(uint_t* __restrict__ xb0_u,
    uint_t* __restrict__ xb1_u){
  uint_t* x = blockIdx.x ? xb1_u : xb0_u;
  for (int idx=threadIdx.x; idx<128*106; idx+=256){
    int rr = idx/106, cc = idx - rr*106;
    x[(size_t)rr*(KP3/2) + 1430 + cc] = 0u;
  }
}

// ---------------- one-time: zero masked alphas ----------------
__global__ __launch_bounds__(256) void k_zeroa(const int* __restrict__ decl_i,
    float* __restrict__ out){
  int b = blockIdx.x, tid = threadIdx.x;
  if (tid >= PP) return;
  for (int t=decl_i[b]; t<TT; t++)
    out[(size_t)OFF_ALPH + ((size_t)b*TT+t)*PP + tid] = 0.f;
}

// ---------------- one-time: att1 -> attb (MFMA; B staged from f32) ----------------
template<bool FULLT>
__global__ __launch_bounds__(256) void k_att1g(const ushort_t* __restrict__ encb,
    const float* __restrict__ enc, const int* __restrict__ sort_i,
    const float* __restrict__ Wea, const float* __restrict__ bea,
    ushort_t* __restrict__ attb){
  __shared__ __align__(16) ushort_t As[128*72];
  __shared__ __align__(16) ushort_t Bs[64*72];
  int tid = threadIdx.x;
  int m0 = blockIdx.x*128, n0 = blockIdx.y*64;
  const int r = tid>>3, c8 = (tid&7)*8;
  const int w = tid>>6, l = tid&63, wm = w>>1, wn = w&1, lr = l&15, lkq = (l>>4)*8;
  f4 acc[4][2] = {};
  for (int k0=0; k0<ENC; k0+=64){
    __syncthreads();
    #pragma unroll
    for (int j=0;j<4;j++){
      int rr = r + j*32, mg = m0 + rr;
      uint4 q;
      if (FULLT){
        q = *(const uint4*)(encb + (size_t)mg*ENC + k0 + c8);
      } else {
        int bq = mg/PP, p = mg - bq*PP;
        const float* src = enc + ((size_t)sort_i[bq]*PP + p)*ENC + k0 + c8;
        float4 f0 = *(const float4*)src, f1 = *(const float4*)(src+4);
        q.x=pack2(f0.x,f0.y); q.y=pack2(f0.z,f0.w); q.z=pack2(f1.x,f1.y); q.w=pack2(f1.z,f1.w);
      }
      *(uint4*)(As + rr*72 + c8) = q;
    }
    #pragma unroll
    for (int j=0;j<2;j++){
      int rr = r + j*32;
      const float* src = Wea + (size_t)(n0+rr)*ENC + k0 + c8;
      float4 f0 = *(const float4*)src, f1 = *(const float4*)(src+4);
      uint4 q; q.x=pack2(f0.x,f0.y); q.y=pack2(f0.z,f0.w); q.z=pack2(f1.x,f1.y); q.w=pack2(f1.z,f1.w);
      *(uint4*)(Bs + rr*72 + c8) = q;
    }
    __syncthreads();
    bf8 b00 = *(const bf8*)(Bs + (wn*32+lr)*72 + lkq);
    bf8 b01 = *(const bf8*)(Bs + (wn*32+lr)*72 + lkq + 32);
    bf8 b10 = *(const bf8*)(Bs + (wn*32+16+lr)*72 + lkq);
    bf8 b11 = *(const bf8*)(Bs + (wn*32+16+lr)*72 + lkq + 32);
    #pragma unroll
    for (int fm=0; fm<4; fm++){
      bf8 a0 = *(const bf8*)(As + (wm*64+fm*16+lr)*72 + lkq);
      bf8 a1 = *(const bf8*)(As + (wm*64+fm*16+lr)*72 + lkq + 32);
      acc[fm][0] = __builtin_amdgcn_mfma_f32_16x16x32_bf16(a0, b00, acc[fm][0], 0,0,0);
      acc[fm][0] = __builtin_amdgcn_mfma_f32_16x16x32_bf16(a1, b01, acc[fm][0], 0,0,0);
      acc[fm][1] = __builtin_amdgcn_mfma_f32_16x16x32_bf16(a0, b10, acc[fm][1], 0,0,0);
      acc[fm][1] = __builtin_amdgcn_mfma_f32_16x16x32_bf16(a1, b11, acc[fm][1], 0,0,0);
    }
  }
  #pragma unroll
  for (int fm=0; fm<4; fm++)
    #pragma unroll
    for (int fn=0; fn<2; fn++)
      #pragma unroll
      for (int rr=0; rr<4; rr++){
        int m = m0 + wm*64 + fm*16 + (l>>4)*4 + rr;
        int n = n0 + wn*32 + fn*16 + (l&15);
        attb[(size_t)m*ATTD + n] = f2b(acc[fm][fn][rr] + bea[n]);
      }
}

// ---------------- persistent step-loop kernel (4 phases / 4 barriers per step) ----------------
template<bool FULLT>
__global__ __launch_bounds__(256) void k_persist(
    ushort_t* __restrict__ xb0, ushort_t* __restrict__ xb1,
    const ushort_t* __restrict__ wkbi, const ushort_t* __restrict__ wcatb,
    const ushort_t* __restrict__ attb, const ushort_t* __restrict__ encb,
    const float* __restrict__ enc, const float* __restrict__ embedding,
    const float* __restrict__ bda, const float* __restrict__ bfb,
    const float* __restrict__ wfa, const float* __restrict__ bfa,
    const float* __restrict__ biasI,
    const int* __restrict__ sort_i, const int* __restrict__ decl_i,
    const int* __restrict__ caps_i, const int* __restrict__ nact_d,
    float* __restrict__ att2s, float* __restrict__ gate,
    float* __restrict__ pbuf, float* __restrict__ c,
    ushort_t* __restrict__ hnball, float* __restrict__ out,
    int* __restrict__ flags, int* __restrict__ rel)
{
  __shared__ __align__(16) ushort_t As[128*72];
  __shared__ __align__(16) ushort_t Bs[64*72];
  int blk = blockIdx.x, tid = threadIdx.x;
  int e = 0;
  const int w = tid>>6, l = tid&63, wm = w>>1, wn = w&1;

  for (int t=0; t<TT; ++t){
    int mb = nact_d[t];
    ushort_t* xbc = (t&1) ? xb1 : xb0;     // current-step input matrix
    ushort_t* xbn = (t&1) ? xb0 : xb1;     // next-step input matrix
    uint_t* xbc_u = (uint_t*)xbc;
    // ===== phase 1: att2+gate GEMM (blk<40)  |  emb -> xbc (40<=blk<104) =====
    if (blk < 40){
      f4 acc[4][2] = {};
      gemmBK64(xbc, KP3, 0, wcatb, 512, blk*64, 0, 512, mb, As, Bs, tid, acc);
      #pragma unroll
      for (int fm=0; fm<4; fm++)
        #pragma unroll
        for (int fn=0; fn<2; fn++)
          #pragma unroll
          for (int rr=0; rr<4; rr++){
            int m = wm*64 + fm*16 + (l>>4)*4 + rr;
            int n = blk*64 + wn*32 + fn*16 + (l&15);
            float v = acc[fm][fn][rr];
            if (n < 512) att2s[m*512+n] = v + bda[n];
            else         gate[m*2048 + (n-512)] = sigf(v + bfb[n-512]);
          }
    } else if (blk < 104){
      int b = (blk-40)*2 + (tid>>7);
      int tok = caps_i[b*CAPLEN+t];
      for (int u=(tid&127); u<150; u+=128){
        float2 em = *(const float2*)(embedding + (size_t)tok*EMB + 2*u);
        xbc_u[b*(KP3/2) + 256 + u] = pack2(em.x, em.y);
      }
    }
    gbar2(flags, rel, ++e, blk, tid);
    // ===== phase 2: score + softmax + alpha + awe*gate -> xbc (blk = b) =====
    {
      int b = blk;
      if (t < decl_i[b]){
        float* sf   = (float*)As;
        float* s_a2 = sf;          float* s_w  = sf+512;
        float* s_sc = sf+1024;     float* s_al = sf+1232;
        float* s_r1 = sf+1440;     float* s_r2 = sf+1448;
        s_a2[tid] = att2s[b*512+tid]; s_a2[256+tid] = att2s[b*512+256+tid];
        s_w[tid]  = wfa[tid];         s_w[256+tid]  = wfa[256+tid];
        __syncthreads();
        int wid = tid>>6, lane = tid&63;
        float b0 = bfa[0];
        for (int p=wid; p<PP; p+=4){
          uint4 q = ((const uint4*)(attb + ((size_t)b*PP + p)*ATTD))[lane];
          int j = lane*8;
          float2 x0=b2x2(q.x), x1=b2x2(q.y), x2=b2x2(q.z), x3=b2x2(q.w);
          float s = fmaxf(x0.x+s_a2[j+0],0.f)*s_w[j+0] + fmaxf(x0.y+s_a2[j+1],0.f)*s_w[j+1]
                  + fmaxf(x1.x+s_a2[j+2],0.f)*s_w[j+2] + fmaxf(x1.y+s_a2[j+3],0.f)*s_w[j+3]
                  + fmaxf(x2.x+s_a2[j+4],0.f)*s_w[j+4] + fmaxf(x2.y+s_a2[j+5],0.f)*s_w[j+5]
                  + fmaxf(x3.x+s_a2[j+6],0.f)*s_w[j+6] + fmaxf(x3.y+s_a2[j+7],0.f)*s_w[j+7];
          #pragma unroll
          for (int off=32;off;off>>=1) s += __shfl_down(s,off);
          if (lane==0) s_sc[p] = s + b0;
        }
        __syncthreads();
        float sc = (tid<PP) ? s_sc[tid] : -1e30f;
        float mx = sc;
        #pragma unroll
        for (int off=32;off;off>>=1) mx = fmaxf(mx, __shfl_down(mx,off));
        if (lane==0) s_r1[wid] = mx;
        __syncthreads();
        mx = fmaxf(fmaxf(s_r1[0],s_r1[1]), fmaxf(s_r1[2],s_r1[3]));
        float eo = (tid<PP) ? expf(sc-mx) : 0.f;
        float sm = eo;
        #pragma unroll
        for (int off=32;off;off>>=1) sm += __shfl_down(sm,off);
        if (lane==0) s_r2[wid] = sm;
        __syncthreads();
        float inv = 1.f/(s_r2[0]+s_r2[1]+s_r2[2]+s_r2[3]);
        if (tid<PP){
          float al = eo*inv;
          s_al[tid] = al;
          out[(size_t)OFF_ALPH + ((size_t)b*TT+t)*PP + tid] = al;
        }
        __syncthreads();
        int ch = tid*8;
        float a0=0.f,a1=0.f,a2=0.f,a3=0.f,a4=0.f,a5=0.f,a6=0.f,a7=0.f;
        if (FULLT){
          const ushort_t* E = encb + (size_t)b*PP*ENC + ch;
          #pragma unroll 2
          for (int p=0;p<PP;p++){
            uint4 q = *(const uint4*)(E + (size_t)p*ENC);
            float al = s_al[p];
            float2 u0=b2x2(q.x),u1=b2x2(q.y),u2=b2x2(q.z),u3=b2x2(q.w);
            a0+=al*u0.x; a1+=al*u0.y; a2+=al*u1.x; a3+=al*u1.y;
            a4+=al*u2.x; a5+=al*u2.y; a6+=al*u3.x; a7+=al*u3.y;
          }
        } else {
          const float* E = enc + ((size_t)sort_i[b]*PP)*ENC + ch;
          #pragma unroll 2
          for (int p=0;p<PP;p++){
            float4 f0 = *(const float4*)(E + (size_t)p*ENC);
            float4 f1 = *(const float4*)(E + (size_t)p*ENC + 4);
            float al = s_al[p];
            a0+=al*f0.x; a1+=al*f0.y; a2+=al*f0.z; a3+=al*f0.w;
            a4+=al*f1.x; a5+=al*f1.y; a6+=al*f1.z; a7+=al*f1.w;
          }
        }
        float4 g0 = *(const float4*)(gate + b*2048 + ch);
        float4 g1 = *(const float4*)(gate + b*2048 + ch + 4);
        uint2 w0, w1;
        w0.x = pack2(a0*g0.x, a1*g0.y); w0.y = pack2(a2*g0.z, a3*g0.w);
        w1.x = pack2(a4*g1.x, a5*g1.y); w1.y = pack2(a6*g1.z, a7*g1.w);
        *(uint2*)(xbc_u + b*(KP3/2) + 406 + tid*4)     = w0;
        *(uint2*)(xbc_u + b*(KP3/2) + 406 + tid*4 + 2) = w1;
      }
    }
    gbar2(flags, rel, ++e, blk, tid);
    // ===== phase 3: gates GEMM split-K=4 over all 128 blocks =====
    {
      int ntile = blk & 31, ks = blk >> 5;
      f4 acc[4][2] = {};
      gemmBK64(xbc, KP3, 0, wkbi, KP3, ntile*64, ks*768, ks*768+768, mb, As, Bs, tid, acc);
      #pragma unroll
      for (int fm=0; fm<4; fm++)
        #pragma unroll
        for (int fn=0; fn<2; fn++)
          #pragma unroll
          for (int rr=0; rr<4; rr++){
            int m = wm*64 + fm*16 + (l>>4)*4 + rr;
            int n = ntile*64 + wn*32 + fn*16 + (l&15);
            pbuf[((size_t)ks*B + m)*2048 + n] = acc[fm][fn][rr];
          }
    }
    gbar2(flags, rel, ++e, blk, tid);
    // ===== phase 4: reduce split-K + LSTM cell (blk<64) =====
    if (blk < 64){
      int slot = blk*256 + tid;       // 0..16383
      int m  = slot >> 7;             // row
      int s4 = slot & 127;            // unit group: units s4*4..+3, pbuf cols s4*16..+15
      int n0 = s4*16;
      f4 q0, q1, q2, q3;
      q0 = *(const f4*)(biasI + n0);     q1 = *(const f4*)(biasI + n0 + 4);
      q2 = *(const f4*)(biasI + n0 + 8); q3 = *(const f4*)(biasI + n0 + 12);
      #pragma unroll
      for (int ks=0; ks<4; ks++){
        const float* p = pbuf + ((size_t)ks*B + m)*2048 + n0;
        q0 += *(const f4*)(p);     q1 += *(const f4*)(p + 4);
        q2 += *(const f4*)(p + 8); q3 += *(const f4*)(p + 12);
      }
      f4 cv = *(const f4*)(c + m*DEC + s4*4);
      float hn[4], cn[4];
      #pragma unroll
      for (int u=0; u<4; u++){
        f4 qq = (u==0)?q0:(u==1)?q1:(u==2)?q2:q3;
        float cc = sigf(qq[1])*cv[u] + sigf(qq[0])*tanhf(qq[2]);
        cn[u] = cc;
        hn[u] = sigf(qq[3])*tanhf(cc);
      }
      int j0 = s4*4;
      *(uint2*)(hnball + ((size_t)t*B + m)*DEC + j0) =
          make_uint2(pack2(hn[0],hn[1]), pack2(hn[2],hn[3]));
      if (t < decl_i[m]){
        f4 cnv = {cn[0], cn[1], cn[2], cn[3]};
        *(f4*)(c + m*DEC + j0) = cnv;
        *(uint2*)(xbn + (size_t)m*KP3 + j0) =
            make_uint2(pack2(hn[0],hn[1]), pack2(hn[2],hn[3]));
      } else {
        *(uint2*)(xbn + (size_t)m*KP3 + j0) = *(const uint2*)(xbc + (size_t)m*KP3 + j0);
      }
    }
    gbar2(flags, rel, ++e, blk, tid);
  }
}

// ---------------- deferred: preds GEMM over all steps (writes zeros for masked rows) ----------------
__global__ __launch_bounds__(256) void k_predall(const ushort_t* __restrict__ hnball,
    const ushort_t* __restrict__ wfcb, const float* __restrict__ b_fc,
    const int* __restrict__ nact_d, float* __restrict__ out){
  __shared__ __align__(16) ushort_t As[128*72];
  __shared__ __align__(16) ushort_t Bs[64*72];
  int tid = threadIdx.x;
  int t = blockIdx.y;
  int n0 = blockIdx.x*64;
  int mb = nact_d[t];
  f4 acc[4][2] = {};
  gemmBK64(hnball + (size_t)t*B*DEC, DEC, 0, wfcb, DEC, n0, 0, DEC, mb, As, Bs, tid, acc);
  int w = tid>>6, l = tid&63, wm = w>>1, wn = w&1;
  #pragma unroll
  for (int fm=0; fm<4; fm++)
    #pragma unroll
    for (int fn=0; fn<2; fn++)
      #pragma unroll
      for (int rr=0; rr<4; rr++){
        int m = wm*64 + fm*16 + (l>>4)*4 + rr;
        int n = n0 + wn*32 + fn*16 + (l&15);
        if (n < VV)
          out[OFF_PRED + ((size_t)m*TT + t)*VV + n] =
              (m < mb) ? (acc[fm][fn][rr] + b_fc[n]) : 0.f;
      }
}

extern "C" void kernel_launch(void* const* d_in, const int* in_sizes, int n_in,
                              void* d_out, int out_size, void* d_ws, size_t ws_size,
                              hipStream_t stream){
  const float* enc       = (const float*)d_in[0];
  const int*   caps_in   = (const int*)d_in[1];
  const int*   caplen    = (const int*)d_in[2];
  const float* W_enc_att = (const float*)d_in[3];
  const float* b_enc_att = (const float*)d_in[4];
  const float* W_dec_att = (const float*)d_in[5];
  const float* b_dec_att = (const float*)d_in[6];
  const float* w_full_att= (const float*)d_in[7];
  const float* b_full_att= (const float*)d_in[8];
  const float* embedding = (const float*)d_in[9];
  const float* W_ih      = (const float*)d_in[10];
  const float* b_ih      = (const float*)d_in[11];
  const float* W_hh      = (const float*)d_in[12];
  const float* b_hh      = (const float*)d_in[13];
  const float* W_init_h  = (const float*)d_in[14];
  const float* b_init_h  = (const float*)d_in[15];
  const float* W_init_c  = (const float*)d_in[16];
  const float* b_init_c  = (const float*)d_in[17];
  const float* W_fbeta   = (const float*)d_in[18];
  const float* b_fbeta   = (const float*)d_in[19];
  const float* W_fc      = (const float*)d_in[20];
  const float* b_fc      = (const float*)d_in[21];
  float* out = (float*)d_out;

  char* base = (char*)d_ws;
  size_t off = 0;
  auto AL = [&](size_t bytes)->void*{ void* p = base + off; off = (off + bytes + 127) & ~127ull; return p; };

  bool FULL = ws_size >= 168000000ull;

  float* c      = (float*)AL(65536*4);
  float* att2s  = (float*)AL(65536*4);
  float* gate   = (float*)AL(262144*4);
  float* pbuf   = (float*)AL((size_t)1048576*4);    // 4 x 128 x 2048 f32
  float* biasI  = (float*)AL(2048*4);
  ushort_t* meanb  = (ushort_t*)AL(262144*2);       // 128 x 2048
  ushort_t* xb0    = (ushort_t*)AL(393216*2);       // 128 x 3072
  ushort_t* xb1    = (ushort_t*)AL(393216*2);       // 128 x 3072
  ushort_t* wkbi   = (ushort_t*)AL((size_t)6291456*2);   // 2048 x 3072 (interleaved)
  ushort_t* wcatb  = (ushort_t*)AL(1310720*2);      // 2560 x 512
  ushort_t* wfcb   = (ushort_t*)AL(5177344*2);      // 10112 x 512
  ushort_t* hnball = (ushort_t*)AL(3276800*2);      // 50 x 128 x 512
  ushort_t* attb   = (ushort_t*)AL((size_t)12845056*2);  // 25088 x 512
  int* sort_i = (int*)AL(128*4);
  int* decl_i = (int*)AL(128*4);
  int* nact_d = (int*)AL(64*4);
  int* caps_i = (int*)AL(6528*4);
  int* flags  = (int*)AL((NBLK*32+32)*4);
  int* rel    = flags + NBLK*32;
  ushort_t* encb = FULL ? (ushort_t*)AL((size_t)51380224*2) : nullptr;   // 25088 x 2048

  k_prep<<<1,128,0,stream>>>(caplen, caps_in, out, sort_i, decl_i, caps_i, nact_d, flags);
  if (FULL) k_encb<<<25088,256,0,stream>>>(enc, sort_i, encb);
  if (FULL) k_mean<true><<<128,256,0,stream>>>(encb, enc, sort_i, meanb);
  else      k_mean<false><<<128,256,0,stream>>>(encb, enc, sort_i, meanb);
  k_initg<<<16,256,0,stream>>>(meanb, W_init_h, b_init_h, W_init_c, b_init_c, c, xb0);
  k_wkbi<<<2048,256,0,stream>>>(W_hh, W_ih, (uint_t*)wkbi);
  k_wcatb<<<2560,256,0,stream>>>(W_dec_att, W_fbeta, (uint_t*)wcatb);
  k_wfcb<<<NPPAD,256,0,stream>>>(W_fc, (uint_t*)wfcb);
  k_biasb<<<8,256,0,stream>>>(b_ih, b_hh, biasI);
  k_xpad<<<2,256,0,stream>>>((uint_t*)xb0, (uint_t*)xb1);
  k_zeroa<<<128,256,0,stream>>>(decl_i, out);
  if (FULL) k_att1g<true><<<dim3(196,8),256,0,stream>>>(encb, enc, sort_i, W_enc_att, b_enc_att, attb);
  else      k_att1g<false><<<dim3(196,8),256,0,stream>>>(encb, enc, sort_i, W_enc_att, b_enc_att, attb);

  if (FULL)
    k_persist<true><<<NBLK,256,0,stream>>>(xb0, xb1, wkbi, wcatb, attb, encb, enc, embedding,
        b_dec_att, b_fbeta, w_full_att, b_full_att, biasI,
        sort_i, decl_i, caps_i, nact_d, att2s, gate, pbuf, c, hnball, out, flags, rel);
  else
    k_persist<false><<<NBLK,256,0,stream>>>(xb0, xb1, wkbi, wcatb, attb, encb, enc, embedding,
        b_dec_att, b_fbeta, w_full_att, b_full_att, biasI,
        sort_i, decl_i, caps_i, nact_d, att2s, gate, pbuf, c, hnball, out, flags, rel);

  k_predall<<<dim3(158,TT),256,0,stream>>>(hnball, wfcb, b_fc, nact_d, out);
}

// Round 9
// 7119.505 us; speedup vs baseline: 1.8620x; 1.4612x over previous
//
#include <hip/hip_runtime.h>
#include <math.h>

#define B 128
#define PP 196
#define ENC 2048
#define DEC 512
#define ATTD 512
#define EMB 300
#define VV 10000
#define CAPLEN 51
#define TT 50
#define KP3 3072           // padded K: 512(h)+300(emb)+2048(gawe)+212 pad (zeroed)
#define NPPAD 10112        // pred N padded to 158*64

static const long long OFF_PRED = 0LL;
static const long long OFF_CAPS = 64000000LL;
static const long long OFF_DECL = 64006528LL;
static const long long OFF_ALPH = 64006656LL;
static const long long OFF_SORT = 65261056LL;

typedef unsigned short ushort_t;
typedef unsigned int uint_t;
typedef short bf8 __attribute__((ext_vector_type(8)));
typedef float f4 __attribute__((ext_vector_type(4)));

__device__ __forceinline__ float sigf(float x){ return 1.f/(1.f+expf(-x)); }
__device__ __forceinline__ float b2f(ushort_t u){
  union{uint_t i; float f;} v; v.i = ((uint_t)u)<<16; return v.f;
}
__device__ __forceinline__ ushort_t f2b(float f){
  union{float f; uint_t i;} v; v.f = f;
  uint_t r = v.i + 0x7fffu + ((v.i>>16)&1u);
  return (ushort_t)(r>>16);
}
__device__ __forceinline__ uint_t pack2(float lo, float hi){
  return (uint_t)f2b(lo) | ((uint_t)f2b(hi)<<16);
}
__device__ __forceinline__ float2 b2x2(uint_t u){
  union{uint_t i; float f;} a,b; a.i = u<<16; b.i = u & 0xffff0000u;
  return make_float2(a.f, b.f);
}

// ======== BK=64 MFMA tile body, 256 thr, tile M=128 N=64, reg-prefetched ========
__device__ __forceinline__ void gemmBK64(
    const ushort_t* __restrict__ Ab, int lda, int m0,
    const ushort_t* __restrict__ Bb, int ldb, int n0,
    int Kbeg, int Kend, int mbound,
    ushort_t* As, ushort_t* Bs, int tid, f4 acc[4][2])
{
  const int r = tid>>3, c8 = (tid&7)*8;
  const int w = tid>>6, l = tid&63;
  const int wm = w>>1, wn = w&1, lr = l&15, lkq = (l>>4)*8;
  uint4 pa[4], pb[2];
  #pragma unroll
  for (int j=0;j<4;j++) pa[j] = *(const uint4*)(Ab + (size_t)(m0 + r + j*32)*lda + Kbeg + c8);
  #pragma unroll
  for (int j=0;j<2;j++) pb[j] = *(const uint4*)(Bb + (size_t)(n0 + r + j*32)*ldb + Kbeg + c8);
  for (int k0=Kbeg; k0<Kend; k0+=64){
    __syncthreads();
    #pragma unroll
    for (int j=0;j<4;j++) *(uint4*)(As + (r+j*32)*72 + c8) = pa[j];
    #pragma unroll
    for (int j=0;j<2;j++) *(uint4*)(Bs + (r+j*32)*72 + c8) = pb[j];
    __syncthreads();
    if (k0+64 < Kend){
      #pragma unroll
      for (int j=0;j<4;j++) pa[j] = *(const uint4*)(Ab + (size_t)(m0 + r + j*32)*lda + k0+64 + c8);
      #pragma unroll
      for (int j=0;j<2;j++) pb[j] = *(const uint4*)(Bb + (size_t)(n0 + r + j*32)*ldb + k0+64 + c8);
    }
    bf8 b00 = *(const bf8*)(Bs + (wn*32+lr)*72 + lkq);
    bf8 b01 = *(const bf8*)(Bs + (wn*32+lr)*72 + lkq + 32);
    bf8 b10 = *(const bf8*)(Bs + (wn*32+16+lr)*72 + lkq);
    bf8 b11 = *(const bf8*)(Bs + (wn*32+16+lr)*72 + lkq + 32);
    #pragma unroll
    for (int fm=0; fm<4; fm++){
      if (wm*64 + fm*16 < mbound){
        bf8 a0 = *(const bf8*)(As + (wm*64+fm*16+lr)*72 + lkq);
        bf8 a1 = *(const bf8*)(As + (wm*64+fm*16+lr)*72 + lkq + 32);
        acc[fm][0] = __builtin_amdgcn_mfma_f32_16x16x32_bf16(a0, b00, acc[fm][0], 0,0,0);
        acc[fm][0] = __builtin_amdgcn_mfma_f32_16x16x32_bf16(a1, b01, acc[fm][0], 0,0,0);
        acc[fm][1] = __builtin_amdgcn_mfma_f32_16x16x32_bf16(a0, b10, acc[fm][1], 0,0,0);
        acc[fm][1] = __builtin_amdgcn_mfma_f32_16x16x32_bf16(a1, b11, acc[fm][1], 0,0,0);
      }
    }
  }
}

// ---------------- sort + caps + decode_lengths + sort_ind + nact + ticket reset ----------------
__global__ __launch_bounds__(128) void k_prep(const int* __restrict__ cap_len,
    const int* __restrict__ enc_caps, float* __restrict__ out,
    int* __restrict__ sort_i, int* __restrict__ decl_i, int* __restrict__ caps_i,
    int* __restrict__ nact_d, int* __restrict__ tickets){
  __shared__ int lens[B];
  __shared__ int sind[B];
  __shared__ int s_dl[B];
  int t = threadIdx.x;
  for (int idx=t; idx<1024; idx+=128) tickets[idx] = 0;
  lens[t] = cap_len[t];
  __syncthreads();
  int my = lens[t];
  int rank = 0;
  for (int j=0;j<B;j++){
    int lj = lens[j];
    if (lj > my || (lj == my && j < t)) rank++;
  }
  sind[rank] = t;
  __syncthreads();
  int src = sind[t];
  sort_i[t] = src;
  int dl = lens[src]-1;
  decl_i[t] = dl;
  s_dl[t] = dl;
  out[OFF_DECL+t] = (float)dl;
  out[OFF_SORT+t] = (float)src;
  for (int j=0;j<CAPLEN;j++){
    int v = enc_caps[src*CAPLEN+j];
    caps_i[t*CAPLEN+j] = v;
    out[OFF_CAPS + t*CAPLEN + j] = (float)v;
  }
  __syncthreads();
  if (t < TT){
    int cnt = 0;
    for (int b2=0;b2<B;b2++) cnt += (s_dl[b2] > t) ? 1 : 0;
    nact_d[t] = cnt;
  }
}

// ---------------- sorted enc -> bf16 ----------------
__global__ __launch_bounds__(256) void k_encb(const float* __restrict__ enc,
    const int* __restrict__ sort_i, ushort_t* __restrict__ encb){
  int row = blockIdx.x;
  int b = row/PP, p = row - b*PP;
  int sb = sort_i[b];
  const float4* s4 = (const float4*)(enc + ((size_t)sb*PP+p)*ENC);
  uint4* d4 = (uint4*)(encb + (size_t)row*ENC);
  int tid = threadIdx.x;
  float4 f0 = s4[tid*2], f1 = s4[tid*2+1];
  uint4 q;
  q.x = pack2(f0.x,f0.y); q.y = pack2(f0.z,f0.w);
  q.z = pack2(f1.x,f1.y); q.w = pack2(f1.z,f1.w);
  d4[tid] = q;
}

// ---------------- mean over P -> meanb bf16 ----------------
template<bool FULLT>
__global__ __launch_bounds__(256) void k_mean(const ushort_t* __restrict__ encb,
    const float* __restrict__ enc, const int* __restrict__ sort_i,
    ushort_t* __restrict__ meanb){
  int b = blockIdx.x, tid = threadIdx.x;
  int ch = tid*8;
  float a[8] = {};
  if (FULLT){
    const ushort_t* E = encb + (size_t)b*PP*ENC + ch;
    for (int p=0;p<PP;p++){
      uint4 q = *(const uint4*)(E + (size_t)p*ENC);
      float2 u0=b2x2(q.x),u1=b2x2(q.y),u2=b2x2(q.z),u3=b2x2(q.w);
      a[0]+=u0.x; a[1]+=u0.y; a[2]+=u1.x; a[3]+=u1.y;
      a[4]+=u2.x; a[5]+=u2.y; a[6]+=u3.x; a[7]+=u3.y;
    }
  } else {
    const float* E = enc + ((size_t)sort_i[b]*PP)*ENC + ch;
    for (int p=0;p<PP;p++){
      float4 f0 = *(const float4*)(E + (size_t)p*ENC);
      float4 f1 = *(const float4*)(E + (size_t)p*ENC + 4);
      a[0]+=f0.x; a[1]+=f0.y; a[2]+=f0.z; a[3]+=f0.w;
      a[4]+=f1.x; a[5]+=f1.y; a[6]+=f1.z; a[7]+=f1.w;
    }
  }
  const float inv = 1.0f/PP;
  uint4 q;
  q.x = pack2(a[0]*inv, a[1]*inv); q.y = pack2(a[2]*inv, a[3]*inv);
  q.z = pack2(a[4]*inv, a[5]*inv); q.w = pack2(a[6]*inv, a[7]*inv);
  *(uint4*)( (uint_t*)meanb + (size_t)b*(ENC/2) + tid*4 ) = q;
}

// ---------------- h0/c0 via MFMA ----------------
__global__ __launch_bounds__(256) void k_initg(const ushort_t* __restrict__ meanb,
    const float* __restrict__ Wh, const float* __restrict__ bh,
    const float* __restrict__ Wc, const float* __restrict__ bc,
    float* __restrict__ c, ushort_t* __restrict__ xb0){
  __shared__ __align__(16) ushort_t As[128*72];
  __shared__ __align__(16) ushort_t Bs[64*72];
  int tid = threadIdx.x;
  int n0 = blockIdx.x*64;
  const int r = tid>>3, c8 = (tid&7)*8;
  const int w = tid>>6, l = tid&63, wm = w>>1, wn = w&1, lr = l&15, lkq = (l>>4)*8;
  f4 acc[4][2] = {};
  for (int k0=0; k0<ENC; k0+=64){
    __syncthreads();
    #pragma unroll
    for (int j=0;j<4;j++){
      int rr = r + j*32;
      *(uint4*)(As + rr*72 + c8) = *(const uint4*)(meanb + (size_t)rr*ENC + k0 + c8);
    }
    #pragma unroll
    for (int j=0;j<2;j++){
      int rr = r + j*32;
      int n = n0 + rr;
      const float* src = (n < 512) ? (Wh + (size_t)n*ENC + k0 + c8)
                                   : (Wc + (size_t)(n-512)*ENC + k0 + c8);
      float4 f0 = *(const float4*)src, f1 = *(const float4*)(src+4);
      uint4 q; q.x=pack2(f0.x,f0.y); q.y=pack2(f0.z,f0.w); q.z=pack2(f1.x,f1.y); q.w=pack2(f1.z,f1.w);
      *(uint4*)(Bs + rr*72 + c8) = q;
    }
    __syncthreads();
    bf8 b00 = *(const bf8*)(Bs + (wn*32+lr)*72 + lkq);
    bf8 b01 = *(const bf8*)(Bs + (wn*32+lr)*72 + lkq + 32);
    bf8 b10 = *(const bf8*)(Bs + (wn*32+16+lr)*72 + lkq);
    bf8 b11 = *(const bf8*)(Bs + (wn*32+16+lr)*72 + lkq + 32);
    #pragma unroll
    for (int fm=0; fm<4; fm++){
      bf8 a0 = *(const bf8*)(As + (wm*64+fm*16+lr)*72 + lkq);
      bf8 a1 = *(const bf8*)(As + (wm*64+fm*16+lr)*72 + lkq + 32);
      acc[fm][0] = __builtin_amdgcn_mfma_f32_16x16x32_bf16(a0, b00, acc[fm][0], 0,0,0);
      acc[fm][0] = __builtin_amdgcn_mfma_f32_16x16x32_bf16(a1, b01, acc[fm][0], 0,0,0);
      acc[fm][1] = __builtin_amdgcn_mfma_f32_16x16x32_bf16(a0, b10, acc[fm][1], 0,0,0);
      acc[fm][1] = __builtin_amdgcn_mfma_f32_16x16x32_bf16(a1, b11, acc[fm][1], 0,0,0);
    }
  }
  #pragma unroll
  for (int fm=0; fm<4; fm++)
    #pragma unroll
    for (int fn=0; fn<2; fn++)
      #pragma unroll
      for (int rr=0; rr<4; rr++){
        int m = wm*64 + fm*16 + (l>>4)*4 + rr;
        int n = n0 + wn*32 + fn*16 + (l&15);
        float v = acc[fm][fn][rr];
        if (n < 512) xb0[(size_t)m*KP3 + n] = f2b(v + bh[n]);
        else         c[m*DEC + (n-512)] = v + bc[n-512];
      }
}

// ---------------- weight converters (one-time) ----------------
// INTERLEAVED gates layout: dst row n = unit j*4+g  <-  src row g*512+j
__global__ __launch_bounds__(256) void k_wkbi(const float* __restrict__ Whh,
    const float* __restrict__ Wih, uint_t* __restrict__ wkb_u){
  int n = blockIdx.x;
  int j = n>>2, g = n&3;
  int srow = g*512 + j;
  uint_t* dst = wkb_u + (size_t)n*(KP3/2);
  for (int u=threadIdx.x; u<KP3/2; u+=256){
    int k = 2*u; float a, bv;
    if (k < 512){ float2 v = *(const float2*)(Whh + (size_t)srow*512 + k); a=v.x; bv=v.y; }
    else if (k < 2860){ float2 v = *(const float2*)(Wih + (size_t)srow*2348 + (k-512)); a=v.x; bv=v.y; }
    else { a=0.f; bv=0.f; }
    dst[u] = pack2(a, bv);
  }
}
__global__ __launch_bounds__(256) void k_wcatb(const float* __restrict__ Wda,
    const float* __restrict__ Wfb, uint_t* __restrict__ wcat_u){
  int n = blockIdx.x;
  const float* src = (n < 512) ? (Wda + (size_t)n*512) : (Wfb + (size_t)(n-512)*512);
  float2 v = *(const float2*)(src + 2*threadIdx.x);
  wcat_u[(size_t)n*256 + threadIdx.x] = pack2(v.x, v.y);
}
__global__ __launch_bounds__(256) void k_wfcb(const float* __restrict__ Wfc,
    uint_t* __restrict__ wfc_u){
  int n = blockIdx.x;
  if (n < VV){
    float2 v = *(const float2*)(Wfc + (size_t)n*512 + 2*threadIdx.x);
    wfc_u[(size_t)n*256 + threadIdx.x] = pack2(v.x, v.y);
  } else wfc_u[(size_t)n*256 + threadIdx.x] = 0u;
}
// interleaved combined LSTM bias: biasI[j*4+g] = b_ih[g*512+j] + b_hh[g*512+j]
__global__ __launch_bounds__(256) void k_biasb(const float* __restrict__ b_ih,
    const float* __restrict__ b_hh, float* __restrict__ biasI){
  int n = blockIdx.x*256 + threadIdx.x;
  int j = n>>2, g = n&3;
  biasI[n] = b_ih[g*512+j] + b_hh[g*512+j];
}
__global__ __launch_bounds__(256) void k_xpad(uint_t* __restrict__ xb0_u,
    uint_t* __restrict__ xb1_u){
  uint_t* x = blockIdx.x ? xb1_u : xb0_u;
  for (int idx=threadIdx.x; idx<128*106; idx+=256){
    int rr = idx/106, cc = idx - rr*106;
    x[(size_t)rr*(KP3/2) + 1430 + cc] = 0u;
  }
}

// ---------------- one-time: zero masked alphas ----------------
__global__ __launch_bounds__(256) void k_zeroa(const int* __restrict__ decl_i,
    float* __restrict__ out){
  int b = blockIdx.x, tid = threadIdx.x;
  if (tid >= PP) return;
  for (int t=decl_i[b]; t<TT; t++)
    out[(size_t)OFF_ALPH + ((size_t)b*TT+t)*PP + tid] = 0.f;
}

// ---------------- one-time: att1 -> attb (MFMA; B staged from f32) ----------------
template<bool FULLT>
__global__ __launch_bounds__(256) void k_att1g(const ushort_t* __restrict__ encb,
    const float* __restrict__ enc, const int* __restrict__ sort_i,
    const float* __restrict__ Wea, const float* __restrict__ bea,
    ushort_t* __restrict__ attb){
  __shared__ __align__(16) ushort_t As[128*72];
  __shared__ __align__(16) ushort_t Bs[64*72];
  int tid = threadIdx.x;
  int m0 = blockIdx.x*128, n0 = blockIdx.y*64;
  const int r = tid>>3, c8 = (tid&7)*8;
  const int w = tid>>6, l = tid&63, wm = w>>1, wn = w&1, lr = l&15, lkq = (l>>4)*8;
  f4 acc[4][2] = {};
  for (int k0=0; k0<ENC; k0+=64){
    __syncthreads();
    #pragma unroll
    for (int j=0;j<4;j++){
      int rr = r + j*32, mg = m0 + rr;
      uint4 q;
      if (FULLT){
        q = *(const uint4*)(encb + (size_t)mg*ENC + k0 + c8);
      } else {
        int bq = mg/PP, p = mg - bq*PP;
        const float* src = enc + ((size_t)sort_i[bq]*PP + p)*ENC + k0 + c8;
        float4 f0 = *(const float4*)src, f1 = *(const float4*)(src+4);
        q.x=pack2(f0.x,f0.y); q.y=pack2(f0.z,f0.w); q.z=pack2(f1.x,f1.y); q.w=pack2(f1.z,f1.w);
      }
      *(uint4*)(As + rr*72 + c8) = q;
    }
    #pragma unroll
    for (int j=0;j<2;j++){
      int rr = r + j*32;
      const float* src = Wea + (size_t)(n0+rr)*ENC + k0 + c8;
      float4 f0 = *(const float4*)src, f1 = *(const float4*)(src+4);
      uint4 q; q.x=pack2(f0.x,f0.y); q.y=pack2(f0.z,f0.w); q.z=pack2(f1.x,f1.y); q.w=pack2(f1.z,f1.w);
      *(uint4*)(Bs + rr*72 + c8) = q;
    }
    __syncthreads();
    bf8 b00 = *(const bf8*)(Bs + (wn*32+lr)*72 + lkq);
    bf8 b01 = *(const bf8*)(Bs + (wn*32+lr)*72 + lkq + 32);
    bf8 b10 = *(const bf8*)(Bs + (wn*32+16+lr)*72 + lkq);
    bf8 b11 = *(const bf8*)(Bs + (wn*32+16+lr)*72 + lkq + 32);
    #pragma unroll
    for (int fm=0; fm<4; fm++){
      bf8 a0 = *(const bf8*)(As + (wm*64+fm*16+lr)*72 + lkq);
      bf8 a1 = *(const bf8*)(As + (wm*64+fm*16+lr)*72 + lkq + 32);
      acc[fm][0] = __builtin_amdgcn_mfma_f32_16x16x32_bf16(a0, b00, acc[fm][0], 0,0,0);
      acc[fm][0] = __builtin_amdgcn_mfma_f32_16x16x32_bf16(a1, b01, acc[fm][0], 0,0,0);
      acc[fm][1] = __builtin_amdgcn_mfma_f32_16x16x32_bf16(a0, b10, acc[fm][1], 0,0,0);
      acc[fm][1] = __builtin_amdgcn_mfma_f32_16x16x32_bf16(a1, b11, acc[fm][1], 0,0,0);
    }
  }
  #pragma unroll
  for (int fm=0; fm<4; fm++)
    #pragma unroll
    for (int fn=0; fn<2; fn++)
      #pragma unroll
      for (int rr=0; rr<4; rr++){
        int m = m0 + wm*64 + fm*16 + (l>>4)*4 + rr;
        int n = n0 + wn*32 + fn*16 + (l&15);
        attb[(size_t)m*ATTD + n] = f2b(acc[fm][fn][rr] + bea[n]);
      }
}

// ---------------- per-step 1: att2+gate GEMM | emb -> xbc ----------------
__global__ __launch_bounds__(256) void k_hmats(const ushort_t* __restrict__ xbc,
    const ushort_t* __restrict__ wcatb, const float* __restrict__ bda,
    const float* __restrict__ bfb, const int* __restrict__ nact_d,
    const int* __restrict__ caps_i, const float* __restrict__ embedding,
    float* __restrict__ att2s, float* __restrict__ gate, int t){
  __shared__ __align__(16) ushort_t As[128*72];
  __shared__ __align__(16) ushort_t Bs[64*72];
  int blk = blockIdx.x, tid = threadIdx.x;
  if (blk < 40){
    int mb = nact_d[t];
    const int w = tid>>6, l = tid&63, wm = w>>1, wn = w&1;
    f4 acc[4][2] = {};
    gemmBK64(xbc, KP3, 0, wcatb, 512, blk*64, 0, 512, mb, As, Bs, tid, acc);
    #pragma unroll
    for (int fm=0; fm<4; fm++)
      #pragma unroll
      for (int fn=0; fn<2; fn++)
        #pragma unroll
        for (int rr=0; rr<4; rr++){
          int m = wm*64 + fm*16 + (l>>4)*4 + rr;
          int n = blk*64 + wn*32 + fn*16 + (l&15);
          float v = acc[fm][fn][rr];
          if (n < 512) att2s[m*512+n] = v + bda[n];
          else         gate[m*2048 + (n-512)] = sigf(v + bfb[n-512]);
        }
  } else {
    int b = (blk-40)*2 + (tid>>7);
    int tok = caps_i[b*CAPLEN+t];
    uint_t* xbc_u = (uint_t*)xbc;
    for (int u=(tid&127); u<150; u+=128){
      float2 em = *(const float2*)(embedding + (size_t)tok*EMB + 2*u);
      xbc_u[b*(KP3/2) + 256 + u] = pack2(em.x, em.y);
    }
  }
}

// ---------------- per-step 2: score + softmax + alpha + awe*gate -> xbc ----------------
template<bool FULLT>
__global__ __launch_bounds__(256) void k_score_awe(const ushort_t* __restrict__ attb,
    const float* __restrict__ att2s, const float* __restrict__ wfa,
    const float* __restrict__ bfa, const int* __restrict__ decl_i,
    const float* __restrict__ gate, const ushort_t* __restrict__ encb,
    const float* __restrict__ enc, const int* __restrict__ sort_i,
    float* __restrict__ out, uint_t* __restrict__ xbc_u, int t){
  int b = blockIdx.x, tid = threadIdx.x;
  if (t >= decl_i[b]) return;
  __shared__ float s_a2[512], s_w[512], s_sc[200], s_al[200], s_r1[8], s_r2[8];
  s_a2[tid] = att2s[b*512+tid]; s_a2[256+tid] = att2s[b*512+256+tid];
  s_w[tid]  = wfa[tid];         s_w[256+tid]  = wfa[256+tid];
  __syncthreads();
  int wid = tid>>6, lane = tid&63;
  float b0 = bfa[0];
  for (int p=wid; p<PP; p+=4){
    uint4 q = ((const uint4*)(attb + ((size_t)b*PP + p)*ATTD))[lane];
    int j = lane*8;
    float2 x0=b2x2(q.x), x1=b2x2(q.y), x2=b2x2(q.z), x3=b2x2(q.w);
    float s = fmaxf(x0.x+s_a2[j+0],0.f)*s_w[j+0] + fmaxf(x0.y+s_a2[j+1],0.f)*s_w[j+1]
            + fmaxf(x1.x+s_a2[j+2],0.f)*s_w[j+2] + fmaxf(x1.y+s_a2[j+3],0.f)*s_w[j+3]
            + fmaxf(x2.x+s_a2[j+4],0.f)*s_w[j+4] + fmaxf(x2.y+s_a2[j+5],0.f)*s_w[j+5]
            + fmaxf(x3.x+s_a2[j+6],0.f)*s_w[j+6] + fmaxf(x3.y+s_a2[j+7],0.f)*s_w[j+7];
    #pragma unroll
    for (int off=32;off;off>>=1) s += __shfl_down(s,off);
    if (lane==0) s_sc[p] = s + b0;
  }
  __syncthreads();
  float sc = (tid<PP) ? s_sc[tid] : -1e30f;
  float mx = sc;
  #pragma unroll
  for (int off=32;off;off>>=1) mx = fmaxf(mx, __shfl_down(mx,off));
  if (lane==0) s_r1[wid] = mx;
  __syncthreads();
  mx = fmaxf(fmaxf(s_r1[0],s_r1[1]), fmaxf(s_r1[2],s_r1[3]));
  float eo = (tid<PP) ? expf(sc-mx) : 0.f;
  float sm = eo;
  #pragma unroll
  for (int off=32;off;off>>=1) sm += __shfl_down(sm,off);
  if (lane==0) s_r2[wid] = sm;
  __syncthreads();
  float inv = 1.f/(s_r2[0]+s_r2[1]+s_r2[2]+s_r2[3]);
  if (tid<PP){
    float al = eo*inv;
    s_al[tid] = al;
    out[(size_t)OFF_ALPH + ((size_t)b*TT+t)*PP + tid] = al;
  }
  __syncthreads();
  int ch = tid*8;
  float a0=0.f,a1=0.f,a2=0.f,a3=0.f,a4=0.f,a5=0.f,a6=0.f,a7=0.f;
  if (FULLT){
    const ushort_t* E = encb + (size_t)b*PP*ENC + ch;
    #pragma unroll 2
    for (int p=0;p<PP;p++){
      uint4 q = *(const uint4*)(E + (size_t)p*ENC);
      float al = s_al[p];
      float2 u0=b2x2(q.x),u1=b2x2(q.y),u2=b2x2(q.z),u3=b2x2(q.w);
      a0+=al*u0.x; a1+=al*u0.y; a2+=al*u1.x; a3+=al*u1.y;
      a4+=al*u2.x; a5+=al*u2.y; a6+=al*u3.x; a7+=al*u3.y;
    }
  } else {
    const float* E = enc + ((size_t)sort_i[b]*PP)*ENC + ch;
    #pragma unroll 2
    for (int p=0;p<PP;p++){
      float4 f0 = *(const float4*)(E + (size_t)p*ENC);
      float4 f1 = *(const float4*)(E + (size_t)p*ENC + 4);
      float al = s_al[p];
      a0+=al*f0.x; a1+=al*f0.y; a2+=al*f0.z; a3+=al*f0.w;
      a4+=al*f1.x; a5+=al*f1.y; a6+=al*f1.z; a7+=al*f1.w;
    }
  }
  float4 g0 = *(const float4*)(gate + b*2048 + ch);
  float4 g1 = *(const float4*)(gate + b*2048 + ch + 4);
  uint2 w0, w1;
  w0.x = pack2(a0*g0.x, a1*g0.y); w0.y = pack2(a2*g0.z, a3*g0.w);
  w1.x = pack2(a4*g1.x, a5*g1.y); w1.y = pack2(a6*g1.z, a7*g1.w);
  *(uint2*)(xbc_u + b*(KP3/2) + 406 + tid*4)     = w0;
  *(uint2*)(xbc_u + b*(KP3/2) + 406 + tid*4 + 2) = w1;
}

// ---------------- per-step 3: gates GEMM split-K=4 + ticket-fused reduce + LSTM ----------------
__global__ __launch_bounds__(256) void k_b1gt(const ushort_t* __restrict__ xbc,
    ushort_t* __restrict__ xbn, const ushort_t* __restrict__ wkbi,
    const float* __restrict__ biasI, const int* __restrict__ decl_i,
    const int* __restrict__ nact_d, float* __restrict__ pbuf,
    float* __restrict__ c, ushort_t* __restrict__ hnball,
    int* __restrict__ tickets, int t){
  __shared__ __align__(16) ushort_t As[128*72];
  __shared__ __align__(16) ushort_t Bs[64*72];
  __shared__ int s_last;
  int blk = blockIdx.x, tid = threadIdx.x;
  int nt = blk & 31, ks = blk >> 5;
  int mb = nact_d[t];
  const int w = tid>>6, l = tid&63, wm = w>>1, wn = w&1;
  f4 acc[4][2] = {};
  gemmBK64(xbc, KP3, 0, wkbi, KP3, nt*64, ks*768, ks*768+768, mb, As, Bs, tid, acc);
  #pragma unroll
  for (int fm=0; fm<4; fm++)
    #pragma unroll
    for (int fn=0; fn<2; fn++)
      #pragma unroll
      for (int rr=0; rr<4; rr++){
        int m = wm*64 + fm*16 + (l>>4)*4 + rr;
        int n = nt*64 + wn*32 + fn*16 + (l&15);
        pbuf[((size_t)ks*B + m)*2048 + n] = acc[fm][fn][rr];
      }
  __syncthreads();     // compiler drains vmcnt(0) before barrier -> stores complete
  if (tid == 0){
    __builtin_amdgcn_fence(__ATOMIC_RELEASE, "agent");
    int old = __hip_atomic_fetch_add(tickets + nt*32, 1, __ATOMIC_ACQ_REL, __HIP_MEMORY_SCOPE_AGENT);
    s_last = (old == 3) ? 1 : 0;
    if (old == 3){
      __hip_atomic_store(tickets + nt*32, 0, __ATOMIC_RELAXED, __HIP_MEMORY_SCOPE_AGENT);
      __builtin_amdgcn_fence(__ATOMIC_ACQUIRE, "agent");
    }
  }
  __syncthreads();
  if (!s_last) return;
  // last arriver: reduce 4 partials for cols [nt*64,+64) = units [nt*16,+16), run LSTM
  #pragma unroll
  for (int q=0; q<8; q++){
    int slot = q*256 + tid;          // 0..2047 = 128 rows x 16 units
    int m = slot >> 4;
    int u = slot & 15;
    int n = nt*64 + u*4;
    int j = nt*16 + u;
    float gi = biasI[n], gf = biasI[n+1], gg = biasI[n+2], go = biasI[n+3];
    #pragma unroll
    for (int s=0;s<4;s++){
      const float* p = pbuf + ((size_t)s*B + m)*2048 + n;
      gi += p[0]; gf += p[1]; gg += p[2]; go += p[3];
    }
    float cc = sigf(gf)*c[m*DEC+j] + sigf(gi)*tanhf(gg);
    float hn = sigf(go)*tanhf(cc);
    hnball[((size_t)t*B + m)*DEC + j] = f2b(hn);
    if (t < decl_i[m]){
      c[m*DEC+j] = cc;
      xbn[(size_t)m*KP3 + j] = f2b(hn);
    } else {
      xbn[(size_t)m*KP3 + j] = xbc[(size_t)m*KP3 + j];
    }
  }
}

// ---------------- deferred: preds GEMM over all steps (zeros for masked rows) ----------------
__global__ __launch_bounds__(256) void k_predall(const ushort_t* __restrict__ hnball,
    const ushort_t* __restrict__ wfcb, const float* __restrict__ b_fc,
    const int* __restrict__ nact_d, float* __restrict__ out){
  __shared__ __align__(16) ushort_t As[128*72];
  __shared__ __align__(16) ushort_t Bs[64*72];
  int tid = threadIdx.x;
  int t = blockIdx.y;
  int n0 = blockIdx.x*64;
  int mb = nact_d[t];
  f4 acc[4][2] = {};
  gemmBK64(hnball + (size_t)t*B*DEC, DEC, 0, wfcb, DEC, n0, 0, DEC, mb, As, Bs, tid, acc);
  int w = tid>>6, l = tid&63, wm = w>>1, wn = w&1;
  #pragma unroll
  for (int fm=0; fm<4; fm++)
    #pragma unroll
    for (int fn=0; fn<2; fn++)
      #pragma unroll
      for (int rr=0; rr<4; rr++){
        int m = wm*64 + fm*16 + (l>>4)*4 + rr;
        int n = n0 + wn*32 + fn*16 + (l&15);
        if (n < VV)
          out[OFF_PRED + ((size_t)m*TT + t)*VV + n] =
              (m < mb) ? (acc[fm][fn][rr] + b_fc[n]) : 0.f;
      }
}

extern "C" void kernel_launch(void* const* d_in, const int* in_sizes, int n_in,
                              void* d_out, int out_size, void* d_ws, size_t ws_size,
                              hipStream_t stream){
  const float* enc       = (const float*)d_in[0];
  const int*   caps_in   = (const int*)d_in[1];
  const int*   caplen    = (const int*)d_in[2];
  const float* W_enc_att = (const float*)d_in[3];
  const float* b_enc_att = (const float*)d_in[4];
  const float* W_dec_att = (const float*)d_in[5];
  const float* b_dec_att = (const float*)d_in[6];
  const float* w_full_att= (const float*)d_in[7];
  const float* b_full_att= (const float*)d_in[8];
  const float* embedding = (const float*)d_in[9];
  const float* W_ih      = (const float*)d_in[10];
  const float* b_ih      = (const float*)d_in[11];
  const float* W_hh      = (const float*)d_in[12];
  const float* b_hh      = (const float*)d_in[13];
  const float* W_init_h  = (const float*)d_in[14];
  const float* b_init_h  = (const float*)d_in[15];
  const float* W_init_c  = (const float*)d_in[16];
  const float* b_init_c  = (const float*)d_in[17];
  const float* W_fbeta   = (const float*)d_in[18];
  const float* b_fbeta   = (const float*)d_in[19];
  const float* W_fc      = (const float*)d_in[20];
  const float* b_fc      = (const float*)d_in[21];
  float* out = (float*)d_out;

  char* base = (char*)d_ws;
  size_t off = 0;
  auto AL = [&](size_t bytes)->void*{ void* p = base + off; off = (off + bytes + 127) & ~127ull; return p; };

  bool FULL = ws_size >= 168000000ull;

  float* c      = (float*)AL(65536*4);
  float* att2s  = (float*)AL(65536*4);
  float* gate   = (float*)AL(262144*4);
  float* pbuf   = (float*)AL((size_t)1048576*4);    // 4 x 128 x 2048 f32
  float* biasI  = (float*)AL(2048*4);
  ushort_t* meanb  = (ushort_t*)AL(262144*2);       // 128 x 2048
  ushort_t* xb0    = (ushort_t*)AL(393216*2);       // 128 x 3072
  ushort_t* xb1    = (ushort_t*)AL(393216*2);       // 128 x 3072
  ushort_t* wkbi   = (ushort_t*)AL((size_t)6291456*2);   // 2048 x 3072 (interleaved)
  ushort_t* wcatb  = (ushort_t*)AL(1310720*2);      // 2560 x 512
  ushort_t* wfcb   = (ushort_t*)AL(5177344*2);      // 10112 x 512
  ushort_t* hnball = (ushort_t*)AL(3276800*2);      // 50 x 128 x 512
  ushort_t* attb   = (ushort_t*)AL((size_t)12845056*2);  // 25088 x 512
  int* sort_i  = (int*)AL(128*4);
  int* decl_i  = (int*)AL(128*4);
  int* nact_d  = (int*)AL(64*4);
  int* caps_i  = (int*)AL(6528*4);
  int* tickets = (int*)AL(1024*4);
  ushort_t* encb = FULL ? (ushort_t*)AL((size_t)51380224*2) : nullptr;   // 25088 x 2048

  k_prep<<<1,128,0,stream>>>(caplen, caps_in, out, sort_i, decl_i, caps_i, nact_d, tickets);
  if (FULL) k_encb<<<25088,256,0,stream>>>(enc, sort_i, encb);
  if (FULL) k_mean<true><<<128,256,0,stream>>>(encb, enc, sort_i, meanb);
  else      k_mean<false><<<128,256,0,stream>>>(encb, enc, sort_i, meanb);
  k_initg<<<16,256,0,stream>>>(meanb, W_init_h, b_init_h, W_init_c, b_init_c, c, xb0);
  k_wkbi<<<2048,256,0,stream>>>(W_hh, W_ih, (uint_t*)wkbi);
  k_wcatb<<<2560,256,0,stream>>>(W_dec_att, W_fbeta, (uint_t*)wcatb);
  k_wfcb<<<NPPAD,256,0,stream>>>(W_fc, (uint_t*)wfcb);
  k_biasb<<<8,256,0,stream>>>(b_ih, b_hh, biasI);
  k_xpad<<<2,256,0,stream>>>((uint_t*)xb0, (uint_t*)xb1);
  k_zeroa<<<128,256,0,stream>>>(decl_i, out);
  if (FULL) k_att1g<true><<<dim3(196,8),256,0,stream>>>(encb, enc, sort_i, W_enc_att, b_enc_att, attb);
  else      k_att1g<false><<<dim3(196,8),256,0,stream>>>(encb, enc, sort_i, W_enc_att, b_enc_att, attb);

  for (int t=0; t<TT; ++t){
    ushort_t* xbc = (t&1) ? xb1 : xb0;
    ushort_t* xbn = (t&1) ? xb0 : xb1;
    k_hmats<<<104,256,0,stream>>>(xbc, wcatb, b_dec_att, b_fbeta, nact_d,
                                  caps_i, embedding, att2s, gate, t);
    if (FULL)
      k_score_awe<true><<<128,256,0,stream>>>(attb, att2s, w_full_att, b_full_att,
          decl_i, gate, encb, enc, sort_i, out, (uint_t*)xbc, t);
    else
      k_score_awe<false><<<128,256,0,stream>>>(attb, att2s, w_full_att, b_full_att,
          decl_i, gate, encb, enc, sort_i, out, (uint_t*)xbc, t);
    k_b1gt<<<128,256,0,stream>>>(xbc, xbn, wkbi, biasI, decl_i, nact_d,
                                 pbuf, c, hnball, tickets, t);
  }
  k_predall<<<dim3(158,TT),256,0,stream>>>(hnball, wfcb, b_fc, nact_d, out);
}